// Round 4
// baseline (1047.559 us; speedup 1.0000x reference)
//
#include <hip/hip_runtime.h>
#include <cstddef>

#define LSLOPE 0.2f
#define BN_EPS 1e-5f

__device__ __forceinline__ float lrelu(float x) { return x > 0.f ? x : LSLOPE * x; }

using short8 = __attribute__((ext_vector_type(8))) short;
using f32x4  = __attribute__((ext_vector_type(4))) float;

__device__ __forceinline__ short f2bf(float x) {
  unsigned u = __float_as_uint(x);
  unsigned r = (u + 0x7fffu + ((u >> 16) & 1u)) >> 16;
  return (short)r;
}
__device__ __forceinline__ float bf2f(short h) {
  return __uint_as_float(((unsigned)(unsigned short)h) << 16);
}
__device__ __forceinline__ void split3(float x, short& h, short& m, short& l) {
  h = f2bf(x);
  float r = x - bf2f(h);
  m = f2bf(r);
  r -= bf2f(m);
  l = f2bf(r);
}

// ---------- 6-term split-bf16 MFMA GEMM: C[N,M] = A[N,K] @ B[K,M] (+bias), M == MCOLS ----------
// A fp32 [N][K], B fp32 [K][M]; both split in-kernel to bf16 hi/mid/lo.
// C = Ah*Bh + Ah*Bm + Am*Bh + Am*Bm + Ah*Bl + Al*Bh  (residual ~2^-24 rel)
template<int MCOLS>
__global__ __launch_bounds__(256) void gemm6_k(const float* __restrict__ A,
                                               const float* __restrict__ B,
                                               float* __restrict__ C, int N, int K,
                                               const float* __restrict__ bias) {
  constexpr int CT  = MCOLS / 16;
  constexpr int LDK = 40;              // 32 + 8 pad (shorts)
  __shared__ __align__(16) short sAh[128 * LDK], sAm[128 * LDK], sAl[128 * LDK];
  __shared__ __align__(16) short sBh[MCOLS * LDK], sBm[MCOLS * LDK], sBl[MCOLS * LDK];

  const int tid  = threadIdx.x;
  const int row0 = blockIdx.x * 128;
  const int wv   = tid >> 6;
  const int lane = tid & 63;
  const int quad = lane >> 4;
  const int mr   = lane & 15;

  f32x4 acc[2][CT];
#pragma unroll
  for (int r = 0; r < 2; ++r)
#pragma unroll
    for (int c = 0; c < CT; ++c) acc[r][c] = (f32x4){0.f, 0.f, 0.f, 0.f};

  for (int kk = 0; kk < K; kk += 32) {
    // stage A tile (128 rows x 32 k) as bf16 hi/mid/lo
#pragma unroll
    for (int cc = 0; cc < 4; ++cc) {
      int s = tid + cc * 256;            // 1024 float4 slots
      int r = s >> 3, kc = (s & 7) << 2;
      float4 v = make_float4(0.f, 0.f, 0.f, 0.f);
      int gr = row0 + r;
      if (gr < N) v = *(const float4*)&A[(size_t)gr * K + kk + kc];
      float vv[4] = {v.x, v.y, v.z, v.w};
#pragma unroll
      for (int i = 0; i < 4; ++i) {
        short h, m, l;
        split3(vv[i], h, m, l);
        sAh[r * LDK + kc + i] = h;
        sAm[r * LDK + kc + i] = m;
        sAl[r * LDK + kc + i] = l;
      }
    }
    // stage B tile (32 k x MCOLS), transposed to [n][k], as bf16 hi/mid/lo
    constexpr int BSLOT = 32 * MCOLS / 4;
    for (int s = tid; s < BSLOT; s += 256) {
      int k  = s / (MCOLS / 4);
      int n0 = (s % (MCOLS / 4)) * 4;
      float4 v = *(const float4*)&B[(size_t)(kk + k) * MCOLS + n0];
      float vv[4] = {v.x, v.y, v.z, v.w};
#pragma unroll
      for (int i = 0; i < 4; ++i) {
        short h, m, l;
        split3(vv[i], h, m, l);
        sBh[(n0 + i) * LDK + k] = h;
        sBm[(n0 + i) * LDK + k] = m;
        sBl[(n0 + i) * LDK + k] = l;
      }
    }
    __syncthreads();

    short8 ah[2], am[2], al[2];
#pragma unroll
    for (int r = 0; r < 2; ++r) {
      int off = (wv * 32 + r * 16 + mr) * LDK + quad * 8;
      ah[r] = *(const short8*)&sAh[off];
      am[r] = *(const short8*)&sAm[off];
      al[r] = *(const short8*)&sAl[off];
    }
#pragma unroll
    for (int c0 = 0; c0 < CT; c0 += 4) {
      short8 bh[4], bm[4], bl[4];
#pragma unroll
      for (int c = 0; c < 4; ++c) {
        int off = ((c0 + c) * 16 + mr) * LDK + quad * 8;
        bh[c] = *(const short8*)&sBh[off];
        bm[c] = *(const short8*)&sBm[off];
        bl[c] = *(const short8*)&sBl[off];
      }
#pragma unroll
      for (int r = 0; r < 2; ++r)
#pragma unroll
        for (int c = 0; c < 4; ++c) {
          f32x4 a = acc[r][c0 + c];
          a = __builtin_amdgcn_mfma_f32_16x16x32_bf16(al[r], bh[c], a, 0, 0, 0);
          a = __builtin_amdgcn_mfma_f32_16x16x32_bf16(ah[r], bl[c], a, 0, 0, 0);
          a = __builtin_amdgcn_mfma_f32_16x16x32_bf16(am[r], bm[c], a, 0, 0, 0);
          a = __builtin_amdgcn_mfma_f32_16x16x32_bf16(am[r], bh[c], a, 0, 0, 0);
          a = __builtin_amdgcn_mfma_f32_16x16x32_bf16(ah[r], bm[c], a, 0, 0, 0);
          a = __builtin_amdgcn_mfma_f32_16x16x32_bf16(ah[r], bh[c], a, 0, 0, 0);
          acc[r][c0 + c] = a;
        }
    }
    __syncthreads();
  }

  // epilogue: D col = lane&15, row = (lane>>4)*4 + reg  [m89/m91-verified]
#pragma unroll
  for (int r = 0; r < 2; ++r)
#pragma unroll
    for (int c = 0; c < CT; ++c)
#pragma unroll
      for (int q = 0; q < 4; ++q) {
        int grow = row0 + wv * 32 + r * 16 + quad * 4 + q;
        if (grow < N) {
          int gcol = c * 16 + mr;
          float val = acc[r][c][q];
          if (bias) val += bias[gcol];
          C[(size_t)grow * MCOLS + gcol] = val;
        }
      }
}

// ---------------- row-wise matvec: out[r] = A[r,:] . v (one wave per row) ----------------
__global__ __launch_bounds__(256) void matvec_k(const float* __restrict__ A, const float* __restrict__ v,
                                                float* __restrict__ out, int R, int K) {
  int w = (blockIdx.x * blockDim.x + threadIdx.x) >> 6;
  int lane = threadIdx.x & 63;
  if (w >= R) return;
  const float* row = A + (size_t)w * K;
  float s = 0.f;
  for (int k = lane; k < K; k += 64) s = fmaf(row[k], v[k], s);
#pragma unroll
  for (int off = 32; off; off >>= 1) s += __shfl_xor(s, off, 64);
  if (lane == 0) out[w] = s;
}

// ---------------- CSR build ----------------
__global__ void deg_count_k(const int* __restrict__ edst, int E, int N, int* __restrict__ deg) {
  int i = blockIdx.x * 256 + threadIdx.x;
  if (i >= E + N) return;
  int d = (i < E) ? edst[i] : (i - E);
  atomicAdd(&deg[d], 1);
}

__global__ __launch_bounds__(1024) void scan1_k(const int* __restrict__ deg, int n,
                                                int* __restrict__ ex, int* __restrict__ bsum) {
  __shared__ int sm[1024];
  int t = threadIdx.x;
  int idx = blockIdx.x * 1024 + t;
  int v = (idx < n) ? deg[idx] : 0;
  sm[t] = v;
  __syncthreads();
  for (int off = 1; off < 1024; off <<= 1) {
    int tv = (t >= off) ? sm[t - off] : 0;
    __syncthreads();
    sm[t] += tv;
    __syncthreads();
  }
  if (idx < n) ex[idx] = sm[t] - v;
  if (t == 1023) bsum[blockIdx.x] = sm[t];
}

__global__ void scan2_k(int* __restrict__ bsum, int nb) {
  if (threadIdx.x == 0 && blockIdx.x == 0) {
    int run = 0;
    for (int b = 0; b < nb; ++b) { int x = bsum[b]; bsum[b] = run; run += x; }
  }
}

__global__ void scan3_k(int* __restrict__ ex, const int* __restrict__ bsum, int n, int total,
                        int* __restrict__ cursor) {
  int idx = blockIdx.x * 256 + threadIdx.x;
  if (idx < n) {
    int v = ex[idx] + bsum[idx >> 10];
    ex[idx] = v;
    cursor[idx] = v;
  }
  if (idx == 0) ex[n] = total;
}

__global__ void scatter_k(const int* __restrict__ esrc, const int* __restrict__ edst, int E, int N,
                          int* __restrict__ cursor, int* __restrict__ csr_src) {
  int i = blockIdx.x * 256 + threadIdx.x;
  if (i >= E + N) return;
  int d, s;
  if (i < E) { d = edst[i]; s = esrc[i]; } else { d = i - E; s = d; }
  int pos = atomicAdd(&cursor[d], 1);
  csr_src[pos] = s;
}

// ---------------- GAT aggregation: one wave per dst node (round-1 float2 version, verbatim) ----------------
__global__ __launch_bounds__(256) void gat_agg_k(const float* __restrict__ hsrc, const float* __restrict__ a_src,
                                                 const float* __restrict__ a_dst, const int* __restrict__ rowstart,
                                                 const int* __restrict__ csr_src, const float* __restrict__ bias,
                                                 float* __restrict__ outp, int N) {
  int w = (blockIdx.x * blockDim.x + threadIdx.x) >> 6;
  int lane = threadIdx.x & 63;
  if (w >= N) return;
  int s0 = rowstart[w];
  int s1 = rowstart[w + 1];
  int deg = s1 - s0;
  float ad = a_dst[w];

  // first (<=64) edges stay in registers
  int sA = 0;
  float eA = -3.0e38f;
  if (lane < deg) {
    sA = csr_src[s0 + lane];
    eA = lrelu(a_src[sA] + ad);
  }
  float m = eA;
  for (int j = s0 + 64 + lane; j < s1; j += 64) {
    int s = csr_src[j];
    m = fmaxf(m, lrelu(a_src[s] + ad));
  }
#pragma unroll
  for (int off = 32; off; off >>= 1) m = fmaxf(m, __shfl_xor(m, off, 64));

  float preg = (lane < deg) ? __expf(eA - m) : 0.f;
  float den = preg;
  for (int j = s0 + 64 + lane; j < s1; j += 64) {
    int s = csr_src[j];
    den += __expf(lrelu(a_src[s] + ad) - m);
  }
#pragma unroll
  for (int off = 32; off; off >>= 1) den += __shfl_xor(den, off, 64);
  float inv = 1.f / den;

  float accx = 0.f, accy = 0.f;
  int lim = deg < 64 ? deg : 64;
  for (int jj = 0; jj < lim; ++jj) {
    int s = __shfl(sA, jj, 64);
    float wgt = __shfl(preg, jj, 64) * inv;
    float2 hv = *(const float2*)&hsrc[(size_t)s * 128 + 2 * lane];
    accx = fmaf(wgt, hv.x, accx);
    accy = fmaf(wgt, hv.y, accy);
  }
  for (int j = s0 + 64; j < s1; ++j) {  // rare: deg > 64
    int s = csr_src[j];
    float wgt = __expf(lrelu(a_src[s] + ad) - m) * inv;
    float2 hv = *(const float2*)&hsrc[(size_t)s * 128 + 2 * lane];
    accx = fmaf(wgt, hv.x, accx);
    accy = fmaf(wgt, hv.y, accy);
  }
  float2 bv = *(const float2*)&bias[2 * lane];
  accx = fmaxf(accx + bv.x, 0.f);
  accy = fmaxf(accy + bv.y, 0.f);
  float2 o; o.x = accx; o.y = accy;
  *(float2*)&outp[(size_t)w * 128 + 2 * lane] = o;
}

// ---------------- BatchNorm stats / finalize ----------------
__global__ __launch_bounds__(256) void bn_stats_k(const float* __restrict__ z, int N,
                                                  float* __restrict__ sums, float* __restrict__ sumsq) {
  __shared__ float ls[256], lq[256];
  int col = threadIdx.x & 63;
  int rg = threadIdx.x >> 6;
  float s = 0.f, q = 0.f;
  for (int r = blockIdx.x * 4 + rg; r < N; r += gridDim.x * 4) {
    float v = z[(size_t)r * 64 + col];
    s += v;
    q = fmaf(v, v, q);
  }
  ls[threadIdx.x] = s;
  lq[threadIdx.x] = q;
  __syncthreads();
  if (threadIdx.x < 64) {
    s = ls[col] + ls[col + 64] + ls[col + 128] + ls[col + 192];
    q = lq[col] + lq[col + 64] + lq[col + 128] + lq[col + 192];
    atomicAdd(&sums[col], s);
    atomicAdd(&sumsq[col], q);
  }
}

__global__ void bn_finalize_k(const float* __restrict__ sums, const float* __restrict__ sumsq,
                              const float* __restrict__ gamma, const float* __restrict__ beta,
                              int N, float* __restrict__ scale, float* __restrict__ shift) {
  int c = threadIdx.x;
  if (c >= 64) return;
  float mean = sums[c] / (float)N;
  float var = sumsq[c] / (float)N - mean * mean;
  float rs = rsqrtf(var + BN_EPS);
  float sc = gamma[c] * rs;
  scale[c] = sc;
  shift[c] = beta[c] - mean * sc;
}

// ---------------- fused BN-apply + ReLU + FC2 + log_softmax (thread per node) ----------------
__global__ __launch_bounds__(256) void fc2_lsm_k(const float* __restrict__ z, const float* __restrict__ scale,
                                                 const float* __restrict__ shift, const float* __restrict__ w,
                                                 const float* __restrict__ b, float* __restrict__ out, int N) {
  int n = blockIdx.x * 256 + threadIdx.x;
  if (n >= N) return;
  float o[40];
#pragma unroll
  for (int c = 0; c < 40; ++c) o[c] = b[c];
  const float* zr = z + (size_t)n * 64;
  for (int k = 0; k < 64; ++k) {
    float v = fmaxf(fmaf(zr[k], scale[k], shift[k]), 0.f);
#pragma unroll
    for (int c = 0; c < 40; ++c) o[c] = fmaf(v, w[k * 40 + c], o[c]);
  }
  float mx = o[0];
#pragma unroll
  for (int c = 1; c < 40; ++c) mx = fmaxf(mx, o[c]);
  float s = 0.f;
#pragma unroll
  for (int c = 0; c < 40; ++c) s += __expf(o[c] - mx);
  float ls = __logf(s);
  float* orow = out + (size_t)n * 40;
#pragma unroll
  for (int c = 0; c < 40; ++c) orow[c] = o[c] - mx - ls;
}

// ---------------- launch (round-1 structure; only the GEMM impl differs) ----------------
extern "C" void kernel_launch(void* const* d_in, const int* in_sizes, int n_in,
                              void* d_out, int out_size, void* d_ws, size_t ws_size,
                              hipStream_t stream) {
  const float* x     = (const float*)d_in[0];
  const int*   eidx  = (const int*)d_in[1];
  const float* W1s   = (const float*)d_in[2];
  const float* W1d   = (const float*)d_in[3];
  const float* att1s = (const float*)d_in[4];
  const float* att1d = (const float*)d_in[5];
  const float* b1    = (const float*)d_in[6];
  const float* W2s   = (const float*)d_in[7];
  const float* W2d   = (const float*)d_in[8];
  const float* att2s = (const float*)d_in[9];
  const float* att2d = (const float*)d_in[10];
  const float* b2    = (const float*)d_in[11];
  const float* fc1w  = (const float*)d_in[12];
  const float* fc1b  = (const float*)d_in[13];
  const float* gamma = (const float*)d_in[14];
  const float* beta  = (const float*)d_in[15];
  const float* fc2w  = (const float*)d_in[16];
  const float* fc2b  = (const float*)d_in[17];
  float* out = (float*)d_out;

  const int N  = in_sizes[0] / 256;
  const int E  = in_sizes[1] / 2;
  const int ET = E + N;
  const int DIN = 256, H1 = 128;

  // workspace layout (~112 MB, identical to round 1)
  char* p = (char*)d_ws;
  const size_t NB = (size_t)N * 128 * sizeof(float);
  float* hA = (float*)p;       p += NB;
  float* hB = (float*)p;       p += NB;
  int* deg      = (int*)p;     p += (size_t)N * 4;
  int* rowstart = (int*)p;     p += (size_t)(N + 1) * 4;
  int* cursor   = (int*)p;     p += (size_t)N * 4;
  int* csr_src  = (int*)p;     p += (size_t)ET * 4;
  float* a_src  = (float*)p;   p += (size_t)N * 4;
  float* a_dst  = (float*)p;   p += (size_t)N * 4;
  float* wv     = (float*)p;   p += 256 * 4;
  float* sums   = (float*)p;   p += 64 * 4;
  float* sumsq  = (float*)p;   p += 64 * 4;
  float* scale  = (float*)p;   p += 64 * 4;
  float* shift  = (float*)p;   p += 64 * 4;
  int* bsum     = (int*)p;     p += 256 * 4;

  const int* esrc = eidx;
  const int* edst = eidx + E;

  // ---- CSR build (by dst, self-loops appended) ----
  hipMemsetAsync(deg, 0, (size_t)N * 4, stream);
  deg_count_k<<<(ET + 255) / 256, 256, 0, stream>>>(edst, E, N, deg);
  int nb = (N + 1023) / 1024;
  scan1_k<<<nb, 1024, 0, stream>>>(deg, N, rowstart, bsum);
  scan2_k<<<1, 64, 0, stream>>>(bsum, nb);
  scan3_k<<<(N + 255) / 256, 256, 0, stream>>>(rowstart, bsum, N, ET, cursor);
  scatter_k<<<(ET + 255) / 256, 256, 0, stream>>>(esrc, edst, E, N, cursor, csr_src);

  const int gemm_blocks = (N + 127) / 128;

  // ---- GAT layer 1 ----
  gemm6_k<128><<<gemm_blocks, 256, 0, stream>>>(x, W1s, hA, N, DIN, (const float*)nullptr);
  matvec_k<<<(DIN + 3) / 4, 256, 0, stream>>>(W1d, att1d, wv, DIN, H1);       // wv = W1_dst @ att1_dst
  matvec_k<<<(N + 3) / 4, 256, 0, stream>>>(x, wv, a_dst, N, DIN);            // a_dst = x @ wv
  matvec_k<<<(N + 3) / 4, 256, 0, stream>>>(hA, att1s, a_src, N, H1);         // a_src = h_src @ att1_src
  gat_agg_k<<<(N + 3) / 4, 256, 0, stream>>>(hA, a_src, a_dst, rowstart, csr_src, b1, hB, N);

  // ---- GAT layer 2 ----
  gemm6_k<128><<<gemm_blocks, 256, 0, stream>>>(hB, W2s, hA, N, H1, (const float*)nullptr);
  matvec_k<<<(H1 + 3) / 4, 256, 0, stream>>>(W2d, att2d, wv, H1, H1);
  matvec_k<<<(N + 3) / 4, 256, 0, stream>>>(hB, wv, a_dst, N, H1);
  matvec_k<<<(N + 3) / 4, 256, 0, stream>>>(hA, att2s, a_src, N, H1);
  gat_agg_k<<<(N + 3) / 4, 256, 0, stream>>>(hA, a_src, a_dst, rowstart, csr_src, b2, hB, N);

  // ---- FC1 (+bias) -> BN -> fused BN-apply+ReLU+FC2+log_softmax ----
  gemm6_k<64><<<gemm_blocks, 256, 0, stream>>>(hB, fc1w, hA, N, H1, fc1b);
  hipMemsetAsync(sums, 0, 128 * sizeof(float), stream);
  bn_stats_k<<<512, 256, 0, stream>>>(hA, N, sums, sumsq);
  bn_finalize_k<<<1, 64, 0, stream>>>(sums, sumsq, gamma, beta, N, scale, shift);
  fc2_lsm_k<<<(N + 255) / 256, 256, 0, stream>>>(hA, scale, shift, fc2w, fc2b, out, N);
}

// Round 6
// 912.406 us; speedup vs baseline: 1.1481x; 1.1481x over previous
//
#include <hip/hip_runtime.h>
#include <cstddef>

#define LSLOPE 0.2f
#define BN_EPS 1e-5f

__device__ __forceinline__ float lrelu(float x) { return x > 0.f ? x : LSLOPE * x; }

using half4 = __attribute__((ext_vector_type(4))) _Float16;
using half8 = __attribute__((ext_vector_type(8))) _Float16;
using f32x4 = __attribute__((ext_vector_type(4))) float;

struct h2 { _Float16 h, l; };
__device__ __forceinline__ h2 split2h(float x) {
  h2 r;
  r.h = (_Float16)x;
  r.l = (_Float16)(x - (float)r.h);
  return r;
}

// ---------- one-time B pre-split into MFMA-frag order ----------
// B [K][M] fp32 -> Bh/Bl f16, layout [c][kb][lane][8] where col=c*16+(lane&15),
// k = kb*32 + (lane>>4)*8 + j. Matches gemm3h_k's per-lane half8 frag loads.
__global__ void bfrag_k(const float* __restrict__ B, _Float16* __restrict__ bh,
                        _Float16* __restrict__ bl, int K, int M) {
  int t = blockIdx.x * 256 + threadIdx.x;
  int KB = K >> 5;
  int total = (M >> 4) * KB * 64;
  if (t >= total) return;
  int lane = t & 63;
  int ckb  = t >> 6;
  int c  = ckb / KB, kb = ckb % KB;
  int mr = lane & 15, quad = lane >> 4;
  int col = c * 16 + mr;
  size_t obase = (size_t)t * 8;
#pragma unroll
  for (int j = 0; j < 8; ++j) {
    int k = kb * 32 + quad * 8 + j;
    h2 s = split2h(B[(size_t)k * M + col]);
    bh[obase + j] = s.h;
    bl[obase + j] = s.l;
  }
}

// ---------- f16 3-term MFMA GEMM: C[N,M] = A[N,K] @ B[K,M] (+bias), M == MCOLS ----------
// C = Ah*Bh + Ah*Bl + Al*Bh  (missing Al*Bl ~ 2^-22 rel: below fp32 noise here)
// A staged in LDS with balanced swizzle; B read as frag-ordered f16 from global (L2-hot).
template<int MCOLS>
__global__ __launch_bounds__(256) void gemm3h_k(const float* __restrict__ A,
                                                const _Float16* __restrict__ Bh,
                                                const _Float16* __restrict__ Bl,
                                                float* __restrict__ C, int N, int K,
                                                const float* __restrict__ bias) {
  constexpr int CT = MCOLS / 16;
  __shared__ __align__(16) _Float16 sAh[128 * 32];
  __shared__ __align__(16) _Float16 sAl[128 * 32];
  const int tid  = threadIdx.x;
  const int row0 = blockIdx.x * 128;
  const int wv   = tid >> 6;
  const int lane = tid & 63;
  const int quad = lane >> 4;
  const int mr   = lane & 15;
  const int KB   = K >> 5;

  f32x4 acc[2][CT];
#pragma unroll
  for (int r = 0; r < 2; ++r)
#pragma unroll
    for (int c = 0; c < CT; ++c) acc[r][c] = (f32x4){0.f, 0.f, 0.f, 0.f};

  for (int kb = 0; kb < KB; ++kb) {
    const int kk = kb << 5;
    // stage A tile (128 rows x 32 k) as f16 hi/lo, swizzled: (r,k) -> r*32 + ((k + r*8)&31)
#pragma unroll
    for (int cc = 0; cc < 4; ++cc) {
      int s = tid + cc * 256;          // 1024 float4 slots
      int r = s >> 3, kc = (s & 7) << 2;
      float4 v = make_float4(0.f, 0.f, 0.f, 0.f);
      int gr = row0 + r;
      if (gr < N) v = *(const float4*)&A[(size_t)gr * K + kk + kc];
      h2 s0 = split2h(v.x);
      h2 s1 = split2h(v.y);
      h2 s2 = split2h(v.z);
      h2 s3 = split2h(v.w);
      half4 h4, l4;
      h4[0] = s0.h; h4[1] = s1.h; h4[2] = s2.h; h4[3] = s3.h;
      l4[0] = s0.l; l4[1] = s1.l; l4[2] = s2.l; l4[3] = s3.l;
      int off = r * 32 + ((kc + r * 8) & 31);   // 4-elem chunk never wraps the 32-ring
      *(half4*)&sAh[off] = h4;
      *(half4*)&sAl[off] = l4;
    }
    __syncthreads();

    half8 ah[2], al[2];
#pragma unroll
    for (int r = 0; r < 2; ++r) {
      int row = wv * 32 + r * 16 + mr;
      int off = row * 32 + ((quad + row) & 3) * 8;
      ah[r] = *(const half8*)&sAh[off];
      al[r] = *(const half8*)&sAl[off];
    }
    const _Float16* bb_h = Bh + ((size_t)kb * 64 + lane) * 8;
    const _Float16* bb_l = Bl + ((size_t)kb * 64 + lane) * 8;
    const size_t cstride = (size_t)KB * 512;   // per col-tile: KB*64*8
#pragma unroll
    for (int c0 = 0; c0 < CT; c0 += 4) {
      half8 bh4[4], bl4[4];
#pragma unroll
      for (int c = 0; c < 4; ++c) {
        size_t o = (size_t)(c0 + c) * cstride;
        bh4[c] = *(const half8*)&bb_h[o];
        bl4[c] = *(const half8*)&bb_l[o];
      }
#pragma unroll
      for (int r = 0; r < 2; ++r)
#pragma unroll
        for (int c = 0; c < 4; ++c) {
          f32x4 a = acc[r][c0 + c];
          a = __builtin_amdgcn_mfma_f32_16x16x32_f16(al[r], bh4[c], a, 0, 0, 0);
          a = __builtin_amdgcn_mfma_f32_16x16x32_f16(ah[r], bl4[c], a, 0, 0, 0);
          a = __builtin_amdgcn_mfma_f32_16x16x32_f16(ah[r], bh4[c], a, 0, 0, 0);
          acc[r][c0 + c] = a;
        }
    }
    __syncthreads();
  }

  // epilogue: D col = lane&15, row = (lane>>4)*4 + reg  [m89/m91-verified]
#pragma unroll
  for (int r = 0; r < 2; ++r)
#pragma unroll
    for (int c = 0; c < CT; ++c)
#pragma unroll
      for (int q = 0; q < 4; ++q) {
        int grow = row0 + wv * 32 + r * 16 + quad * 4 + q;
        if (grow < N) {
          int gcol = c * 16 + mr;
          float val = acc[r][c][q];
          if (bias) val += bias[gcol];
          C[(size_t)grow * MCOLS + gcol] = val;
        }
      }
}

// ---------------- row-wise matvec: out[r] = A[r,:] . v (one wave per row) ----------------
__global__ __launch_bounds__(256) void matvec_k(const float* __restrict__ A, const float* __restrict__ v,
                                                float* __restrict__ out, int R, int K) {
  int w = (blockIdx.x * blockDim.x + threadIdx.x) >> 6;
  int lane = threadIdx.x & 63;
  if (w >= R) return;
  const float* row = A + (size_t)w * K;
  float s = 0.f;
  for (int k = lane; k < K; k += 64) s = fmaf(row[k], v[k], s);
#pragma unroll
  for (int off = 32; off; off >>= 1) s += __shfl_xor(s, off, 64);
  if (lane == 0) out[w] = s;
}

// ---------------- CSR build ----------------
__global__ void deg_count_k(const int* __restrict__ edst, int E, int N, int* __restrict__ deg) {
  int i = blockIdx.x * 256 + threadIdx.x;
  if (i >= E + N) return;
  int d = (i < E) ? edst[i] : (i - E);
  atomicAdd(&deg[d], 1);
}

__global__ __launch_bounds__(1024) void scan1_k(const int* __restrict__ deg, int n,
                                                int* __restrict__ ex, int* __restrict__ bsum) {
  __shared__ int sm[1024];
  int t = threadIdx.x;
  int idx = blockIdx.x * 1024 + t;
  int v = (idx < n) ? deg[idx] : 0;
  sm[t] = v;
  __syncthreads();
  for (int off = 1; off < 1024; off <<= 1) {
    int tv = (t >= off) ? sm[t - off] : 0;
    __syncthreads();
    sm[t] += tv;
    __syncthreads();
  }
  if (idx < n) ex[idx] = sm[t] - v;
  if (t == 1023) bsum[blockIdx.x] = sm[t];
}

__global__ void scan2_k(int* __restrict__ bsum, int nb) {
  if (threadIdx.x == 0 && blockIdx.x == 0) {
    int run = 0;
    for (int b = 0; b < nb; ++b) { int x = bsum[b]; bsum[b] = run; run += x; }
  }
}

__global__ void scan3_k(int* __restrict__ ex, const int* __restrict__ bsum, int n, int total,
                        int* __restrict__ cursor) {
  int idx = blockIdx.x * 256 + threadIdx.x;
  if (idx < n) {
    int v = ex[idx] + bsum[idx >> 10];
    ex[idx] = v;
    cursor[idx] = v;
  }
  if (idx == 0) ex[n] = total;
}

__global__ void scatter_k(const int* __restrict__ esrc, const int* __restrict__ edst, int E, int N,
                          int* __restrict__ cursor, int* __restrict__ csr_src) {
  int i = blockIdx.x * 256 + threadIdx.x;
  if (i >= E + N) return;
  int d, s;
  if (i < E) { d = edst[i]; s = esrc[i]; } else { d = i - E; s = d; }
  int pos = atomicAdd(&cursor[d], 1);
  csr_src[pos] = s;
}

// ---------------- GAT aggregation: one wave per dst node (round-1/4 float2 version, verbatim) ----------------
__global__ __launch_bounds__(256) void gat_agg_k(const float* __restrict__ hsrc, const float* __restrict__ a_src,
                                                 const float* __restrict__ a_dst, const int* __restrict__ rowstart,
                                                 const int* __restrict__ csr_src, const float* __restrict__ bias,
                                                 float* __restrict__ outp, int N) {
  int w = (blockIdx.x * blockDim.x + threadIdx.x) >> 6;
  int lane = threadIdx.x & 63;
  if (w >= N) return;
  int s0 = rowstart[w];
  int s1 = rowstart[w + 1];
  int deg = s1 - s0;
  float ad = a_dst[w];

  int sA = 0;
  float eA = -3.0e38f;
  if (lane < deg) {
    sA = csr_src[s0 + lane];
    eA = lrelu(a_src[sA] + ad);
  }
  float m = eA;
  for (int j = s0 + 64 + lane; j < s1; j += 64) {
    int s = csr_src[j];
    m = fmaxf(m, lrelu(a_src[s] + ad));
  }
#pragma unroll
  for (int off = 32; off; off >>= 1) m = fmaxf(m, __shfl_xor(m, off, 64));

  float preg = (lane < deg) ? __expf(eA - m) : 0.f;
  float den = preg;
  for (int j = s0 + 64 + lane; j < s1; j += 64) {
    int s = csr_src[j];
    den += __expf(lrelu(a_src[s] + ad) - m);
  }
#pragma unroll
  for (int off = 32; off; off >>= 1) den += __shfl_xor(den, off, 64);
  float inv = 1.f / den;

  float accx = 0.f, accy = 0.f;
  int lim = deg < 64 ? deg : 64;
  for (int jj = 0; jj < lim; ++jj) {
    int s = __shfl(sA, jj, 64);
    float wgt = __shfl(preg, jj, 64) * inv;
    float2 hv = *(const float2*)&hsrc[(size_t)s * 128 + 2 * lane];
    accx = fmaf(wgt, hv.x, accx);
    accy = fmaf(wgt, hv.y, accy);
  }
  for (int j = s0 + 64; j < s1; ++j) {  // rare: deg > 64
    int s = csr_src[j];
    float wgt = __expf(lrelu(a_src[s] + ad) - m) * inv;
    float2 hv = *(const float2*)&hsrc[(size_t)s * 128 + 2 * lane];
    accx = fmaf(wgt, hv.x, accx);
    accy = fmaf(wgt, hv.y, accy);
  }
  float2 bv = *(const float2*)&bias[2 * lane];
  accx = fmaxf(accx + bv.x, 0.f);
  accy = fmaxf(accy + bv.y, 0.f);
  float2 o; o.x = accx; o.y = accy;
  *(float2*)&outp[(size_t)w * 128 + 2 * lane] = o;
}

// ---------------- BatchNorm stats / finalize ----------------
__global__ __launch_bounds__(256) void bn_stats_k(const float* __restrict__ z, int N,
                                                  float* __restrict__ sums, float* __restrict__ sumsq) {
  __shared__ float ls[256], lq[256];
  int col = threadIdx.x & 63;
  int rg = threadIdx.x >> 6;
  float s = 0.f, q = 0.f;
  for (int r = blockIdx.x * 4 + rg; r < N; r += gridDim.x * 4) {
    float v = z[(size_t)r * 64 + col];
    s += v;
    q = fmaf(v, v, q);
  }
  ls[threadIdx.x] = s;
  lq[threadIdx.x] = q;
  __syncthreads();
  if (threadIdx.x < 64) {
    s = ls[col] + ls[col + 64] + ls[col + 128] + ls[col + 192];
    q = lq[col] + lq[col + 64] + lq[col + 128] + lq[col + 192];
    atomicAdd(&sums[col], s);
    atomicAdd(&sumsq[col], q);
  }
}

__global__ void bn_finalize_k(const float* __restrict__ sums, const float* __restrict__ sumsq,
                              const float* __restrict__ gamma, const float* __restrict__ beta,
                              int N, float* __restrict__ scale, float* __restrict__ shift) {
  int c = threadIdx.x;
  if (c >= 64) return;
  float mean = sums[c] / (float)N;
  float var = sumsq[c] / (float)N - mean * mean;
  float rs = rsqrtf(var + BN_EPS);
  float sc = gamma[c] * rs;
  scale[c] = sc;
  shift[c] = beta[c] - mean * sc;
}

// ---------------- fused BN-apply + ReLU + FC2 + log_softmax (thread per node) ----------------
__global__ __launch_bounds__(256) void fc2_lsm_k(const float* __restrict__ z, const float* __restrict__ scale,
                                                 const float* __restrict__ shift, const float* __restrict__ w,
                                                 const float* __restrict__ b, float* __restrict__ out, int N) {
  int n = blockIdx.x * 256 + threadIdx.x;
  if (n >= N) return;
  float o[40];
#pragma unroll
  for (int c = 0; c < 40; ++c) o[c] = b[c];
  const float* zr = z + (size_t)n * 64;
  for (int k = 0; k < 64; ++k) {
    float v = fmaxf(fmaf(zr[k], scale[k], shift[k]), 0.f);
#pragma unroll
    for (int c = 0; c < 40; ++c) o[c] = fmaf(v, w[k * 40 + c], o[c]);
  }
  float mx = o[0];
#pragma unroll
  for (int c = 1; c < 40; ++c) mx = fmaxf(mx, o[c]);
  float s = 0.f;
#pragma unroll
  for (int c = 0; c < 40; ++c) s += __expf(o[c] - mx);
  float ls = __logf(s);
  float* orow = out + (size_t)n * 40;
#pragma unroll
  for (int c = 0; c < 40; ++c) orow[c] = o[c] - mx - ls;
}

// ---------------- launch ----------------
static inline char* al16(char* p) { return (char*)(((size_t)p + 15) & ~(size_t)15); }

extern "C" void kernel_launch(void* const* d_in, const int* in_sizes, int n_in,
                              void* d_out, int out_size, void* d_ws, size_t ws_size,
                              hipStream_t stream) {
  const float* x     = (const float*)d_in[0];
  const int*   eidx  = (const int*)d_in[1];
  const float* W1s   = (const float*)d_in[2];
  const float* W1d   = (const float*)d_in[3];
  const float* att1s = (const float*)d_in[4];
  const float* att1d = (const float*)d_in[5];
  const float* b1    = (const float*)d_in[6];
  const float* W2s   = (const float*)d_in[7];
  const float* W2d   = (const float*)d_in[8];
  const float* att2s = (const float*)d_in[9];
  const float* att2d = (const float*)d_in[10];
  const float* b2    = (const float*)d_in[11];
  const float* fc1w  = (const float*)d_in[12];
  const float* fc1b  = (const float*)d_in[13];
  const float* gamma = (const float*)d_in[14];
  const float* beta  = (const float*)d_in[15];
  const float* fc2w  = (const float*)d_in[16];
  const float* fc2b  = (const float*)d_in[17];
  float* out = (float*)d_out;

  const int N  = in_sizes[0] / 256;
  const int E  = in_sizes[1] / 2;
  const int ET = E + N;
  const int DIN = 256, H1 = 128;

  // workspace layout (~113 MB)
  char* p = (char*)d_ws;
  const size_t NB = (size_t)N * 128 * sizeof(float);
  float* hA = (float*)p;       p += NB;
  float* hB = (float*)p;       p += NB;
  int* deg      = (int*)p;     p += (size_t)N * 4;
  int* rowstart = (int*)p;     p += (size_t)(N + 1) * 4;
  int* cursor   = (int*)p;     p += (size_t)N * 4;
  int* csr_src  = (int*)p;     p += (size_t)ET * 4;
  float* a_src  = (float*)p;   p += (size_t)N * 4;
  float* a_dst  = (float*)p;   p += (size_t)N * 4;
  float* wv     = (float*)p;   p += 256 * 4;
  float* sums   = (float*)p;   p += 64 * 4;
  float* sumsq  = (float*)p;   p += 64 * 4;
  float* scale  = (float*)p;   p += 64 * 4;
  float* shift  = (float*)p;   p += 64 * 4;
  int* bsum     = (int*)p;     p += 256 * 4;
  p = al16(p);
  _Float16* B1h = (_Float16*)p; p += (size_t)256 * 128 * 2;
  _Float16* B1l = (_Float16*)p; p += (size_t)256 * 128 * 2;
  _Float16* B2h = (_Float16*)p; p += (size_t)128 * 128 * 2;
  _Float16* B2l = (_Float16*)p; p += (size_t)128 * 128 * 2;
  _Float16* Bfh = (_Float16*)p; p += (size_t)128 * 64 * 2;
  _Float16* Bfl = (_Float16*)p; p += (size_t)128 * 64 * 2;

  const int* esrc = eidx;
  const int* edst = eidx + E;

  // ---- CSR build (by dst, self-loops appended) ----
  hipMemsetAsync(deg, 0, (size_t)N * 4, stream);
  deg_count_k<<<(ET + 255) / 256, 256, 0, stream>>>(edst, E, N, deg);
  int nb = (N + 1023) / 1024;
  scan1_k<<<nb, 1024, 0, stream>>>(deg, N, rowstart, bsum);
  scan2_k<<<1, 64, 0, stream>>>(bsum, nb);
  scan3_k<<<(N + 255) / 256, 256, 0, stream>>>(rowstart, bsum, N, ET, cursor);
  scatter_k<<<(ET + 255) / 256, 256, 0, stream>>>(esrc, edst, E, N, cursor, csr_src);

  // ---- one-time B frag pre-splits (tiny) ----
  bfrag_k<<<16, 256, 0, stream>>>(W1s, B1h, B1l, 256, 128);
  bfrag_k<<<8, 256, 0, stream>>>(W2s, B2h, B2l, 128, 128);
  bfrag_k<<<4, 256, 0, stream>>>(fc1w, Bfh, Bfl, 128, 64);

  const int gemm_blocks = (N + 127) / 128;

  // ---- GAT layer 1 ----
  gemm3h_k<128><<<gemm_blocks, 256, 0, stream>>>(x, B1h, B1l, hA, N, DIN, (const float*)nullptr);
  matvec_k<<<(DIN + 3) / 4, 256, 0, stream>>>(W1d, att1d, wv, DIN, H1);       // wv = W1_dst @ att1_dst
  matvec_k<<<(N + 3) / 4, 256, 0, stream>>>(x, wv, a_dst, N, DIN);            // a_dst = x @ wv
  matvec_k<<<(N + 3) / 4, 256, 0, stream>>>(hA, att1s, a_src, N, H1);         // a_src = h_src @ att1_src
  gat_agg_k<<<(N + 3) / 4, 256, 0, stream>>>(hA, a_src, a_dst, rowstart, csr_src, b1, hB, N);

  // ---- GAT layer 2 ----
  gemm3h_k<128><<<gemm_blocks, 256, 0, stream>>>(hB, B2h, B2l, hA, N, H1, (const float*)nullptr);
  matvec_k<<<(H1 + 3) / 4, 256, 0, stream>>>(W2d, att2d, wv, H1, H1);
  matvec_k<<<(N + 3) / 4, 256, 0, stream>>>(hB, wv, a_dst, N, H1);
  matvec_k<<<(N + 3) / 4, 256, 0, stream>>>(hA, att2s, a_src, N, H1);
  gat_agg_k<<<(N + 3) / 4, 256, 0, stream>>>(hA, a_src, a_dst, rowstart, csr_src, b2, hB, N);

  // ---- FC1 (+bias) -> BN -> fused BN-apply+ReLU+FC2+log_softmax ----
  gemm3h_k<64><<<gemm_blocks, 256, 0, stream>>>(hB, Bfh, Bfl, hA, N, H1, fc1b);
  hipMemsetAsync(sums, 0, 128 * sizeof(float), stream);
  bn_stats_k<<<512, 256, 0, stream>>>(hA, N, sums, sumsq);
  bn_finalize_k<<<1, 64, 0, stream>>>(sums, sumsq, gamma, beta, N, scale, shift);
  fc2_lsm_k<<<(N + 255) / 256, 256, 0, stream>>>(hA, scale, shift, fc2w, fc2b, out, N);
}

// Round 7
// 872.834 us; speedup vs baseline: 1.2002x; 1.0453x over previous
//
#include <hip/hip_runtime.h>
#include <cstddef>

#define LSLOPE 0.2f
#define BN_EPS 1e-5f

__device__ __forceinline__ float lrelu(float x) { return x > 0.f ? x : LSLOPE * x; }

using half4 = __attribute__((ext_vector_type(4))) _Float16;
using half8 = __attribute__((ext_vector_type(8))) _Float16;
using f32x4 = __attribute__((ext_vector_type(4))) float;

struct h2 { _Float16 h, l; };
__device__ __forceinline__ h2 split2h(float x) {
  h2 r;
  r.h = (_Float16)x;
  r.l = (_Float16)(x - (float)r.h);
  return r;
}

__device__ __forceinline__ unsigned short f2bf(float x) {
  unsigned u = __float_as_uint(x);
  unsigned r = (u + 0x7fffu + ((u >> 16) & 1u)) >> 16;
  return (unsigned short)r;
}

// ---------- one-time B pre-split into MFMA-frag order ----------
__global__ void bfrag_k(const float* __restrict__ B, _Float16* __restrict__ bh,
                        _Float16* __restrict__ bl, int K, int M) {
  int t = blockIdx.x * 256 + threadIdx.x;
  int KB = K >> 5;
  int total = (M >> 4) * KB * 64;
  if (t >= total) return;
  int lane = t & 63;
  int ckb  = t >> 6;
  int c  = ckb / KB, kb = ckb % KB;
  int mr = lane & 15, quad = lane >> 4;
  int col = c * 16 + mr;
  size_t obase = (size_t)t * 8;
#pragma unroll
  for (int j = 0; j < 8; ++j) {
    int k = kb * 32 + quad * 8 + j;
    h2 s = split2h(B[(size_t)k * M + col]);
    bh[obase + j] = s.h;
    bl[obase + j] = s.l;
  }
}

// ---------- f16 3-term MFMA GEMM: C[N,M] = A[N,K] @ B[K,M] (+bias), M == MCOLS ----------
// Optional outputs: Cf fp32 [N][MCOLS], Cbf bf16 [N][128] (requires MCOLS==128),
// asrc[row] = C_row . attv (fused attention dot).
template<int MCOLS>
__global__ __launch_bounds__(256) void gemm3h_k(const float* __restrict__ A,
                                                const _Float16* __restrict__ Bh,
                                                const _Float16* __restrict__ Bl,
                                                float* __restrict__ Cf,
                                                unsigned short* __restrict__ Cbf,
                                                const float* __restrict__ attv,
                                                float* __restrict__ asrc,
                                                int N, int K,
                                                const float* __restrict__ bias) {
  constexpr int CT = MCOLS / 16;
  __shared__ __align__(16) _Float16 sAh[128 * 32];
  __shared__ __align__(16) _Float16 sAl[128 * 32];
  const int tid  = threadIdx.x;
  const int row0 = blockIdx.x * 128;
  const int wv   = tid >> 6;
  const int lane = tid & 63;
  const int quad = lane >> 4;
  const int mr   = lane & 15;
  const int KB   = K >> 5;

  f32x4 acc[2][CT];
#pragma unroll
  for (int r = 0; r < 2; ++r)
#pragma unroll
    for (int c = 0; c < CT; ++c) acc[r][c] = (f32x4){0.f, 0.f, 0.f, 0.f};

  for (int kb = 0; kb < KB; ++kb) {
    const int kk = kb << 5;
#pragma unroll
    for (int cc = 0; cc < 4; ++cc) {
      int s = tid + cc * 256;
      int r = s >> 3, kc = (s & 7) << 2;
      float4 v = make_float4(0.f, 0.f, 0.f, 0.f);
      int gr = row0 + r;
      if (gr < N) v = *(const float4*)&A[(size_t)gr * K + kk + kc];
      h2 s0 = split2h(v.x);
      h2 s1 = split2h(v.y);
      h2 s2 = split2h(v.z);
      h2 s3 = split2h(v.w);
      half4 h4, l4;
      h4[0] = s0.h; h4[1] = s1.h; h4[2] = s2.h; h4[3] = s3.h;
      l4[0] = s0.l; l4[1] = s1.l; l4[2] = s2.l; l4[3] = s3.l;
      int off = r * 32 + ((kc + r * 8) & 31);
      *(half4*)&sAh[off] = h4;
      *(half4*)&sAl[off] = l4;
    }
    __syncthreads();

    half8 ah[2], al[2];
#pragma unroll
    for (int r = 0; r < 2; ++r) {
      int row = wv * 32 + r * 16 + mr;
      int off = row * 32 + ((quad + row) & 3) * 8;
      ah[r] = *(const half8*)&sAh[off];
      al[r] = *(const half8*)&sAl[off];
    }
    const _Float16* bb_h = Bh + ((size_t)kb * 64 + lane) * 8;
    const _Float16* bb_l = Bl + ((size_t)kb * 64 + lane) * 8;
    const size_t cstride = (size_t)KB * 512;
#pragma unroll
    for (int c0 = 0; c0 < CT; c0 += 4) {
      half8 bh4[4], bl4[4];
#pragma unroll
      for (int c = 0; c < 4; ++c) {
        size_t o = (size_t)(c0 + c) * cstride;
        bh4[c] = *(const half8*)&bb_h[o];
        bl4[c] = *(const half8*)&bb_l[o];
      }
#pragma unroll
      for (int r = 0; r < 2; ++r)
#pragma unroll
        for (int c = 0; c < 4; ++c) {
          f32x4 a = acc[r][c0 + c];
          a = __builtin_amdgcn_mfma_f32_16x16x32_f16(al[r], bh4[c], a, 0, 0, 0);
          a = __builtin_amdgcn_mfma_f32_16x16x32_f16(ah[r], bl4[c], a, 0, 0, 0);
          a = __builtin_amdgcn_mfma_f32_16x16x32_f16(ah[r], bh4[c], a, 0, 0, 0);
          acc[r][c0 + c] = a;
        }
    }
    __syncthreads();
  }

  // epilogue: D col = lane&15, row = (lane>>4)*4 + reg  [m89/m91-verified]
  float pa[2][4];
#pragma unroll
  for (int r = 0; r < 2; ++r)
#pragma unroll
    for (int q = 0; q < 4; ++q) pa[r][q] = 0.f;

#pragma unroll
  for (int r = 0; r < 2; ++r)
#pragma unroll
    for (int c = 0; c < CT; ++c) {
      float av = attv ? attv[c * 16 + mr] : 0.f;
#pragma unroll
      for (int q = 0; q < 4; ++q) {
        int grow = row0 + wv * 32 + r * 16 + quad * 4 + q;
        float val = acc[r][c][q];
        if (bias) val += bias[c * 16 + mr];
        if (grow < N) {
          int gcol = c * 16 + mr;
          if (Cf)  Cf[(size_t)grow * MCOLS + gcol] = val;
          if (Cbf) Cbf[(size_t)grow * 128 + gcol] = f2bf(val);
        }
        if (attv) pa[r][q] = fmaf(val, av, pa[r][q]);
      }
    }
  if (attv) {
#pragma unroll
    for (int r = 0; r < 2; ++r)
#pragma unroll
      for (int q = 0; q < 4; ++q) {
        float p2 = pa[r][q];
        p2 += __shfl_xor(p2, 1, 64);
        p2 += __shfl_xor(p2, 2, 64);
        p2 += __shfl_xor(p2, 4, 64);
        p2 += __shfl_xor(p2, 8, 64);
        int grow = row0 + wv * 32 + r * 16 + quad * 4 + q;
        if (mr == 0 && grow < N) asrc[grow] = p2;
      }
  }
}

// ---------------- row-wise matvec: out[r] = A[r,:] . v (one wave per row) ----------------
__global__ __launch_bounds__(256) void matvec_k(const float* __restrict__ A, const float* __restrict__ v,
                                                float* __restrict__ out, int R, int K) {
  int w = (blockIdx.x * blockDim.x + threadIdx.x) >> 6;
  int lane = threadIdx.x & 63;
  if (w >= R) return;
  const float* row = A + (size_t)w * K;
  float s = 0.f;
  for (int k = lane; k < K; k += 64) s = fmaf(row[k], v[k], s);
#pragma unroll
  for (int off = 32; off; off >>= 1) s += __shfl_xor(s, off, 64);
  if (lane == 0) out[w] = s;
}

// ---------------- CSR build ----------------
__global__ void deg_count_k(const int* __restrict__ edst, int E, int N, int* __restrict__ deg) {
  int i = blockIdx.x * 256 + threadIdx.x;
  if (i >= E + N) return;
  int d = (i < E) ? edst[i] : (i - E);
  atomicAdd(&deg[d], 1);
}

__global__ __launch_bounds__(1024) void scan1_k(const int* __restrict__ deg, int n,
                                                int* __restrict__ ex, int* __restrict__ bsum) {
  __shared__ int sm[1024];
  int t = threadIdx.x;
  int idx = blockIdx.x * 1024 + t;
  int v = (idx < n) ? deg[idx] : 0;
  sm[t] = v;
  __syncthreads();
  for (int off = 1; off < 1024; off <<= 1) {
    int tv = (t >= off) ? sm[t - off] : 0;
    __syncthreads();
    sm[t] += tv;
    __syncthreads();
  }
  if (idx < n) ex[idx] = sm[t] - v;
  if (t == 1023) bsum[blockIdx.x] = sm[t];
}

__global__ void scan2_k(int* __restrict__ bsum, int nb) {
  if (threadIdx.x == 0 && blockIdx.x == 0) {
    int run = 0;
    for (int b = 0; b < nb; ++b) { int x = bsum[b]; bsum[b] = run; run += x; }
  }
}

__global__ void scan3_k(int* __restrict__ ex, const int* __restrict__ bsum, int n, int total,
                        int* __restrict__ cursor) {
  int idx = blockIdx.x * 256 + threadIdx.x;
  if (idx < n) {
    int v = ex[idx] + bsum[idx >> 10];
    ex[idx] = v;
    cursor[idx] = v;
  }
  if (idx == 0) ex[n] = total;
}

__global__ void scatter_k(const int* __restrict__ esrc, const int* __restrict__ edst, int E, int N,
                          int* __restrict__ cursor, int* __restrict__ csr_src) {
  int i = blockIdx.x * 256 + threadIdx.x;
  if (i >= E + N) return;
  int d, s;
  if (i < E) { d = edst[i]; s = esrc[i]; } else { d = i - E; s = d; }
  int pos = atomicAdd(&cursor[d], 1);
  csr_src[pos] = s;
}

// ---------------- GAT aggregation: one wave per dst node; h_src gathered as bf16 ----------------
__global__ __launch_bounds__(256) void gat_agg_k(const unsigned short* __restrict__ hbf,
                                                 const float* __restrict__ a_src,
                                                 const float* __restrict__ a_dst, const int* __restrict__ rowstart,
                                                 const int* __restrict__ csr_src, const float* __restrict__ bias,
                                                 float* __restrict__ outp, int N) {
  int w = (blockIdx.x * blockDim.x + threadIdx.x) >> 6;
  int lane = threadIdx.x & 63;
  if (w >= N) return;
  int s0 = rowstart[w];
  int s1 = rowstart[w + 1];
  int deg = s1 - s0;
  float ad = a_dst[w];

  int sA = 0;
  float eA = -3.0e38f;
  if (lane < deg) {
    sA = csr_src[s0 + lane];
    eA = lrelu(a_src[sA] + ad);
  }
  float m = eA;
  for (int j = s0 + 64 + lane; j < s1; j += 64) {
    int s = csr_src[j];
    m = fmaxf(m, lrelu(a_src[s] + ad));
  }
#pragma unroll
  for (int off = 32; off; off >>= 1) m = fmaxf(m, __shfl_xor(m, off, 64));

  float preg = (lane < deg) ? __expf(eA - m) : 0.f;
  float den = preg;
  for (int j = s0 + 64 + lane; j < s1; j += 64) {
    int s = csr_src[j];
    den += __expf(lrelu(a_src[s] + ad) - m);
  }
#pragma unroll
  for (int off = 32; off; off >>= 1) den += __shfl_xor(den, off, 64);
  float inv = 1.f / den;

  const unsigned int* hrow = (const unsigned int*)hbf;   // 64 uints (=128 bf16) per row
  float accx = 0.f, accy = 0.f;
  int lim = deg < 64 ? deg : 64;
  for (int jj = 0; jj < lim; ++jj) {
    int s = __shfl(sA, jj, 64);
    float wgt = __shfl(preg, jj, 64) * inv;
    unsigned int u = hrow[(size_t)s * 64 + lane];
    float lo = __uint_as_float(u << 16);
    float hi = __uint_as_float(u & 0xffff0000u);
    accx = fmaf(wgt, lo, accx);
    accy = fmaf(wgt, hi, accy);
  }
  for (int j = s0 + 64; j < s1; ++j) {  // rare: deg > 64
    int s = csr_src[j];
    float wgt = __expf(lrelu(a_src[s] + ad) - m) * inv;
    unsigned int u = hrow[(size_t)s * 64 + lane];
    float lo = __uint_as_float(u << 16);
    float hi = __uint_as_float(u & 0xffff0000u);
    accx = fmaf(wgt, lo, accx);
    accy = fmaf(wgt, hi, accy);
  }
  float2 bv = *(const float2*)&bias[2 * lane];
  accx = fmaxf(accx + bv.x, 0.f);
  accy = fmaxf(accy + bv.y, 0.f);
  float2 o; o.x = accx; o.y = accy;
  *(float2*)&outp[(size_t)w * 128 + 2 * lane] = o;
}

// ---------------- BatchNorm stats / finalize ----------------
__global__ __launch_bounds__(256) void bn_stats_k(const float* __restrict__ z, int N,
                                                  float* __restrict__ sums, float* __restrict__ sumsq) {
  __shared__ float ls[256], lq[256];
  int col = threadIdx.x & 63;
  int rg = threadIdx.x >> 6;
  float s = 0.f, q = 0.f;
  for (int r = blockIdx.x * 4 + rg; r < N; r += gridDim.x * 4) {
    float v = z[(size_t)r * 64 + col];
    s += v;
    q = fmaf(v, v, q);
  }
  ls[threadIdx.x] = s;
  lq[threadIdx.x] = q;
  __syncthreads();
  if (threadIdx.x < 64) {
    s = ls[col] + ls[col + 64] + ls[col + 128] + ls[col + 192];
    q = lq[col] + lq[col + 64] + lq[col + 128] + lq[col + 192];
    atomicAdd(&sums[col], s);
    atomicAdd(&sumsq[col], q);
  }
}

__global__ void bn_finalize_k(const float* __restrict__ sums, const float* __restrict__ sumsq,
                              const float* __restrict__ gamma, const float* __restrict__ beta,
                              int N, float* __restrict__ scale, float* __restrict__ shift) {
  int c = threadIdx.x;
  if (c >= 64) return;
  float mean = sums[c] / (float)N;
  float var = sumsq[c] / (float)N - mean * mean;
  float rs = rsqrtf(var + BN_EPS);
  float sc = gamma[c] * rs;
  scale[c] = sc;
  shift[c] = beta[c] - mean * sc;
}

// ---------------- fused BN-apply + ReLU + FC2 + log_softmax (thread per node) ----------------
__global__ __launch_bounds__(256) void fc2_lsm_k(const float* __restrict__ z, const float* __restrict__ scale,
                                                 const float* __restrict__ shift, const float* __restrict__ w,
                                                 const float* __restrict__ b, float* __restrict__ out, int N) {
  int n = blockIdx.x * 256 + threadIdx.x;
  if (n >= N) return;
  float o[40];
#pragma unroll
  for (int c = 0; c < 40; ++c) o[c] = b[c];
  const float* zr = z + (size_t)n * 64;
  for (int k = 0; k < 64; ++k) {
    float v = fmaxf(fmaf(zr[k], scale[k], shift[k]), 0.f);
#pragma unroll
    for (int c = 0; c < 40; ++c) o[c] = fmaf(v, w[k * 40 + c], o[c]);
  }
  float mx = o[0];
#pragma unroll
  for (int c = 1; c < 40; ++c) mx = fmaxf(mx, o[c]);
  float s = 0.f;
#pragma unroll
  for (int c = 0; c < 40; ++c) s += __expf(o[c] - mx);
  float ls = __logf(s);
  float* orow = out + (size_t)n * 40;
#pragma unroll
  for (int c = 0; c < 40; ++c) orow[c] = o[c] - mx - ls;
}

// ---------------- launch ----------------
static inline char* al16(char* p) { return (char*)(((size_t)p + 15) & ~(size_t)15); }

extern "C" void kernel_launch(void* const* d_in, const int* in_sizes, int n_in,
                              void* d_out, int out_size, void* d_ws, size_t ws_size,
                              hipStream_t stream) {
  const float* x     = (const float*)d_in[0];
  const int*   eidx  = (const int*)d_in[1];
  const float* W1s   = (const float*)d_in[2];
  const float* W1d   = (const float*)d_in[3];
  const float* att1s = (const float*)d_in[4];
  const float* att1d = (const float*)d_in[5];
  const float* b1    = (const float*)d_in[6];
  const float* W2s   = (const float*)d_in[7];
  const float* W2d   = (const float*)d_in[8];
  const float* att2s = (const float*)d_in[9];
  const float* att2d = (const float*)d_in[10];
  const float* b2    = (const float*)d_in[11];
  const float* fc1w  = (const float*)d_in[12];
  const float* fc1b  = (const float*)d_in[13];
  const float* gamma = (const float*)d_in[14];
  const float* beta  = (const float*)d_in[15];
  const float* fc2w  = (const float*)d_in[16];
  const float* fc2b  = (const float*)d_in[17];
  float* out = (float*)d_out;

  const int N  = in_sizes[0] / 256;
  const int E  = in_sizes[1] / 2;
  const int ET = E + N;
  const int DIN = 256, H1 = 128;

  // workspace layout (~115 MB)
  char* p = (char*)d_ws;
  float* hB = (float*)p;               p += (size_t)N * 128 * 4;   // fp32 agg output (h after relu+bias)
  float* hF = (float*)p;               p += (size_t)N * 64 * 4;    // fp32 FC1 output
  unsigned short* bhA = (unsigned short*)p; p += (size_t)N * 128 * 2; // bf16 gemm output (gather source)
  int* deg      = (int*)p;     p += (size_t)N * 4;
  int* rowstart = (int*)p;     p += (size_t)(N + 1) * 4;
  int* cursor   = (int*)p;     p += (size_t)N * 4;
  int* csr_src  = (int*)p;     p += (size_t)ET * 4;
  float* a_src  = (float*)p;   p += (size_t)N * 4;
  float* a_dst  = (float*)p;   p += (size_t)N * 4;
  float* wvd1   = (float*)p;   p += 256 * 4;
  float* wvd2   = (float*)p;   p += 128 * 4;
  float* sums   = (float*)p;   p += 64 * 4;
  float* sumsq  = (float*)p;   p += 64 * 4;
  float* scale  = (float*)p;   p += 64 * 4;
  float* shift  = (float*)p;   p += 64 * 4;
  int* bsum     = (int*)p;     p += 256 * 4;
  p = al16(p);
  _Float16* B1h = (_Float16*)p; p += (size_t)256 * 128 * 2;
  _Float16* B1l = (_Float16*)p; p += (size_t)256 * 128 * 2;
  _Float16* B2h = (_Float16*)p; p += (size_t)128 * 128 * 2;
  _Float16* B2l = (_Float16*)p; p += (size_t)128 * 128 * 2;
  _Float16* Bfh = (_Float16*)p; p += (size_t)128 * 64 * 2;
  _Float16* Bfl = (_Float16*)p; p += (size_t)128 * 64 * 2;

  const int* esrc = eidx;
  const int* edst = eidx + E;

  // ---- CSR build (by dst, self-loops appended) ----
  hipMemsetAsync(deg, 0, (size_t)N * 4, stream);
  deg_count_k<<<(ET + 255) / 256, 256, 0, stream>>>(edst, E, N, deg);
  int nb = (N + 1023) / 1024;
  scan1_k<<<nb, 1024, 0, stream>>>(deg, N, rowstart, bsum);
  scan2_k<<<1, 64, 0, stream>>>(bsum, nb);
  scan3_k<<<(N + 255) / 256, 256, 0, stream>>>(rowstart, bsum, N, ET, cursor);
  scatter_k<<<(ET + 255) / 256, 256, 0, stream>>>(esrc, edst, E, N, cursor, csr_src);

  // ---- one-time B frag pre-splits + a_dst fold vectors ----
  bfrag_k<<<16, 256, 0, stream>>>(W1s, B1h, B1l, 256, 128);
  bfrag_k<<<8, 256, 0, stream>>>(W2s, B2h, B2l, 128, 128);
  bfrag_k<<<4, 256, 0, stream>>>(fc1w, Bfh, Bfl, 128, 64);
  matvec_k<<<64, 256, 0, stream>>>(W1d, att1d, wvd1, 256, 128);   // wvd1 = W1_dst @ att1_dst
  matvec_k<<<32, 256, 0, stream>>>(W2d, att2d, wvd2, 128, 128);

  const int gemm_blocks = (N + 127) / 128;

  // ---- GAT layer 1: gemm writes bf16 h + fused a_src; a_dst via folded matvec ----
  gemm3h_k<128><<<gemm_blocks, 256, 0, stream>>>(x, B1h, B1l, (float*)nullptr, bhA, att1s, a_src,
                                                 N, DIN, (const float*)nullptr);
  matvec_k<<<(N + 3) / 4, 256, 0, stream>>>(x, wvd1, a_dst, N, DIN);
  gat_agg_k<<<(N + 3) / 4, 256, 0, stream>>>(bhA, a_src, a_dst, rowstart, csr_src, b1, hB, N);

  // ---- GAT layer 2 ----
  gemm3h_k<128><<<gemm_blocks, 256, 0, stream>>>(hB, B2h, B2l, (float*)nullptr, bhA, att2s, a_src,
                                                 N, H1, (const float*)nullptr);
  matvec_k<<<(N + 3) / 4, 256, 0, stream>>>(hB, wvd2, a_dst, N, H1);
  gat_agg_k<<<(N + 3) / 4, 256, 0, stream>>>(bhA, a_src, a_dst, rowstart, csr_src, b2, hB, N);

  // ---- FC1 (+bias) -> BN -> fused BN-apply+ReLU+FC2+log_softmax ----
  gemm3h_k<64><<<gemm_blocks, 256, 0, stream>>>(hB, Bfh, Bfl, hF, (unsigned short*)nullptr,
                                                (const float*)nullptr, (float*)nullptr, N, H1, fc1b);
  hipMemsetAsync(sums, 0, 128 * sizeof(float), stream);
  bn_stats_k<<<512, 256, 0, stream>>>(hF, N, sums, sumsq);
  bn_finalize_k<<<1, 64, 0, stream>>>(sums, sumsq, gamma, beta, N, scale, shift);
  fc2_lsm_k<<<(N + 255) / 256, 256, 0, stream>>>(hF, scale, shift, fc2w, fc2b, out, N);
}

// Round 8
// 853.430 us; speedup vs baseline: 1.2275x; 1.0227x over previous
//
#include <hip/hip_runtime.h>
#include <cstddef>

#define LSLOPE 0.2f
#define BN_EPS 1e-5f

__device__ __forceinline__ float lrelu(float x) { return x > 0.f ? x : LSLOPE * x; }

using half4 = __attribute__((ext_vector_type(4))) _Float16;
using half8 = __attribute__((ext_vector_type(8))) _Float16;
using f32x4 = __attribute__((ext_vector_type(4))) float;

struct h2 { _Float16 h, l; };
__device__ __forceinline__ h2 split2h(float x) {
  h2 r;
  r.h = (_Float16)x;
  r.l = (_Float16)(x - (float)r.h);
  return r;
}

__device__ __forceinline__ unsigned short f2bf(float x) {
  unsigned u = __float_as_uint(x);
  unsigned r = (u + 0x7fffu + ((u >> 16) & 1u)) >> 16;
  return (unsigned short)r;
}

// ---------- one-time B pre-split into MFMA-frag order ----------
__global__ void bfrag_k(const float* __restrict__ B, _Float16* __restrict__ bh,
                        _Float16* __restrict__ bl, int K, int M) {
  int t = blockIdx.x * 256 + threadIdx.x;
  int KB = K >> 5;
  int total = (M >> 4) * KB * 64;
  if (t >= total) return;
  int lane = t & 63;
  int ckb  = t >> 6;
  int c  = ckb / KB, kb = ckb % KB;
  int mr = lane & 15, quad = lane >> 4;
  int col = c * 16 + mr;
  size_t obase = (size_t)t * 8;
#pragma unroll
  for (int j = 0; j < 8; ++j) {
    int k = kb * 32 + quad * 8 + j;
    h2 s = split2h(B[(size_t)k * M + col]);
    bh[obase + j] = s.h;
    bl[obase + j] = s.l;
  }
}

// ---------- f16 3-term MFMA GEMM: C[N,M] = A[N,K] @ B[K,M] (+bias), M == MCOLS ----------
// Optional outputs: Cf fp32, Cbf bf16 (requires MCOLS==128), asrc[row] = C_row . attv.
template<int MCOLS>
__global__ __launch_bounds__(256) void gemm3h_k(const float* __restrict__ A,
                                                const _Float16* __restrict__ Bh,
                                                const _Float16* __restrict__ Bl,
                                                float* __restrict__ Cf,
                                                unsigned short* __restrict__ Cbf,
                                                const float* __restrict__ attv,
                                                float* __restrict__ asrc,
                                                int N, int K,
                                                const float* __restrict__ bias) {
  constexpr int CT = MCOLS / 16;
  __shared__ __align__(16) _Float16 sAh[128 * 32];
  __shared__ __align__(16) _Float16 sAl[128 * 32];
  const int tid  = threadIdx.x;
  const int row0 = blockIdx.x * 128;
  const int wv   = tid >> 6;
  const int lane = tid & 63;
  const int quad = lane >> 4;
  const int mr   = lane & 15;
  const int KB   = K >> 5;

  f32x4 acc[2][CT];
#pragma unroll
  for (int r = 0; r < 2; ++r)
#pragma unroll
    for (int c = 0; c < CT; ++c) acc[r][c] = (f32x4){0.f, 0.f, 0.f, 0.f};

  for (int kb = 0; kb < KB; ++kb) {
    const int kk = kb << 5;
#pragma unroll
    for (int cc = 0; cc < 4; ++cc) {
      int s = tid + cc * 256;
      int r = s >> 3, kc = (s & 7) << 2;
      float4 v = make_float4(0.f, 0.f, 0.f, 0.f);
      int gr = row0 + r;
      if (gr < N) v = *(const float4*)&A[(size_t)gr * K + kk + kc];
      h2 s0 = split2h(v.x);
      h2 s1 = split2h(v.y);
      h2 s2 = split2h(v.z);
      h2 s3 = split2h(v.w);
      half4 h4, l4;
      h4[0] = s0.h; h4[1] = s1.h; h4[2] = s2.h; h4[3] = s3.h;
      l4[0] = s0.l; l4[1] = s1.l; l4[2] = s2.l; l4[3] = s3.l;
      int off = r * 32 + ((kc + r * 8) & 31);
      *(half4*)&sAh[off] = h4;
      *(half4*)&sAl[off] = l4;
    }
    __syncthreads();

    half8 ah[2], al[2];
#pragma unroll
    for (int r = 0; r < 2; ++r) {
      int row = wv * 32 + r * 16 + mr;
      int off = row * 32 + ((quad + row) & 3) * 8;
      ah[r] = *(const half8*)&sAh[off];
      al[r] = *(const half8*)&sAl[off];
    }
    const _Float16* bb_h = Bh + ((size_t)kb * 64 + lane) * 8;
    const _Float16* bb_l = Bl + ((size_t)kb * 64 + lane) * 8;
    const size_t cstride = (size_t)KB * 512;
#pragma unroll
    for (int c0 = 0; c0 < CT; c0 += 4) {
      half8 bh4[4], bl4[4];
#pragma unroll
      for (int c = 0; c < 4; ++c) {
        size_t o = (size_t)(c0 + c) * cstride;
        bh4[c] = *(const half8*)&bb_h[o];
        bl4[c] = *(const half8*)&bb_l[o];
      }
#pragma unroll
      for (int r = 0; r < 2; ++r)
#pragma unroll
        for (int c = 0; c < 4; ++c) {
          f32x4 a = acc[r][c0 + c];
          a = __builtin_amdgcn_mfma_f32_16x16x32_f16(al[r], bh4[c], a, 0, 0, 0);
          a = __builtin_amdgcn_mfma_f32_16x16x32_f16(ah[r], bl4[c], a, 0, 0, 0);
          a = __builtin_amdgcn_mfma_f32_16x16x32_f16(ah[r], bh4[c], a, 0, 0, 0);
          acc[r][c0 + c] = a;
        }
    }
    __syncthreads();
  }

  // epilogue: D col = lane&15, row = (lane>>4)*4 + reg  [m89/m91-verified]
  float pa[2][4];
#pragma unroll
  for (int r = 0; r < 2; ++r)
#pragma unroll
    for (int q = 0; q < 4; ++q) pa[r][q] = 0.f;

#pragma unroll
  for (int r = 0; r < 2; ++r)
#pragma unroll
    for (int c = 0; c < CT; ++c) {
      float av = attv ? attv[c * 16 + mr] : 0.f;
#pragma unroll
      for (int q = 0; q < 4; ++q) {
        int grow = row0 + wv * 32 + r * 16 + quad * 4 + q;
        float val = acc[r][c][q];
        if (bias) val += bias[c * 16 + mr];
        if (grow < N) {
          int gcol = c * 16 + mr;
          if (Cf)  Cf[(size_t)grow * MCOLS + gcol] = val;
          if (Cbf) Cbf[(size_t)grow * 128 + gcol] = f2bf(val);
        }
        if (attv) pa[r][q] = fmaf(val, av, pa[r][q]);
      }
    }
  if (attv) {
#pragma unroll
    for (int r = 0; r < 2; ++r)
#pragma unroll
      for (int q = 0; q < 4; ++q) {
        float p2 = pa[r][q];
        p2 += __shfl_xor(p2, 1, 64);
        p2 += __shfl_xor(p2, 2, 64);
        p2 += __shfl_xor(p2, 4, 64);
        p2 += __shfl_xor(p2, 8, 64);
        int grow = row0 + wv * 32 + r * 16 + quad * 4 + q;
        if (mr == 0 && grow < N) asrc[grow] = p2;
      }
  }
}

// ---------------- row-wise matvec: out[r] = A[r,:] . v (one wave per row) ----------------
__global__ __launch_bounds__(256) void matvec_k(const float* __restrict__ A, const float* __restrict__ v,
                                                float* __restrict__ out, int R, int K) {
  int w = (blockIdx.x * blockDim.x + threadIdx.x) >> 6;
  int lane = threadIdx.x & 63;
  if (w >= R) return;
  const float* row = A + (size_t)w * K;
  float s = 0.f;
  for (int k = lane; k < K; k += 64) s = fmaf(row[k], v[k], s);
#pragma unroll
  for (int off = 32; off; off >>= 1) s += __shfl_xor(s, off, 64);
  if (lane == 0) out[w] = s;
}

// ---------------- CSR build ----------------
__global__ void deg_count_k(const int* __restrict__ edst, int E, int N, int* __restrict__ deg) {
  int i = blockIdx.x * 256 + threadIdx.x;
  if (i >= E + N) return;
  int d = (i < E) ? edst[i] : (i - E);
  atomicAdd(&deg[d], 1);
}

__global__ __launch_bounds__(1024) void scan1_k(const int* __restrict__ deg, int n,
                                                int* __restrict__ ex, int* __restrict__ bsum) {
  __shared__ int sm[1024];
  int t = threadIdx.x;
  int idx = blockIdx.x * 1024 + t;
  int v = (idx < n) ? deg[idx] : 0;
  sm[t] = v;
  __syncthreads();
  for (int off = 1; off < 1024; off <<= 1) {
    int tv = (t >= off) ? sm[t - off] : 0;
    __syncthreads();
    sm[t] += tv;
    __syncthreads();
  }
  if (idx < n) ex[idx] = sm[t] - v;
  if (t == 1023) bsum[blockIdx.x] = sm[t];
}

__global__ void scan2_k(int* __restrict__ bsum, int nb) {
  if (threadIdx.x == 0 && blockIdx.x == 0) {
    int run = 0;
    for (int b = 0; b < nb; ++b) { int x = bsum[b]; bsum[b] = run; run += x; }
  }
}

__global__ void scan3_k(int* __restrict__ ex, const int* __restrict__ bsum, int n, int total,
                        int* __restrict__ cursor) {
  int idx = blockIdx.x * 256 + threadIdx.x;
  if (idx < n) {
    int v = ex[idx] + bsum[idx >> 10];
    ex[idx] = v;
    cursor[idx] = v;
  }
  if (idx == 0) ex[n] = total;
}

// range-filtered scatter: only edges with dst in [d0,d1) are placed. Launched
// NR times sequentially so each pass's write region (~ET/NR*4B) merges in L2.
__global__ void scatter_range_k(const int* __restrict__ esrc, const int* __restrict__ edst,
                                int E, int N, int d0, int d1,
                                int* __restrict__ cursor, int* __restrict__ csr_src) {
  int i = blockIdx.x * 256 + threadIdx.x;
  if (i >= E + N) return;
  int d = (i < E) ? edst[i] : (i - E);
  if (d < d0 || d >= d1) return;
  int s = (i < E) ? esrc[i] : d;
  int pos = atomicAdd(&cursor[d], 1);
  csr_src[pos] = s;
}

// ---------------- GAT aggregation: one wave per dst node; h_src gathered as bf16 ----------------
__global__ __launch_bounds__(256) void gat_agg_k(const unsigned short* __restrict__ hbf,
                                                 const float* __restrict__ a_src,
                                                 const float* __restrict__ a_dst, const int* __restrict__ rowstart,
                                                 const int* __restrict__ csr_src, const float* __restrict__ bias,
                                                 float* __restrict__ outp, int N) {
  int w = (blockIdx.x * blockDim.x + threadIdx.x) >> 6;
  int lane = threadIdx.x & 63;
  if (w >= N) return;
  int s0 = rowstart[w];
  int s1 = rowstart[w + 1];
  int deg = s1 - s0;
  float ad = a_dst[w];

  int sA = 0;
  float eA = -3.0e38f;
  if (lane < deg) {
    sA = csr_src[s0 + lane];
    eA = lrelu(a_src[sA] + ad);
  }
  float m = eA;
  for (int j = s0 + 64 + lane; j < s1; j += 64) {
    int s = csr_src[j];
    m = fmaxf(m, lrelu(a_src[s] + ad));
  }
#pragma unroll
  for (int off = 32; off; off >>= 1) m = fmaxf(m, __shfl_xor(m, off, 64));

  float preg = (lane < deg) ? __expf(eA - m) : 0.f;
  float den = preg;
  for (int j = s0 + 64 + lane; j < s1; j += 64) {
    int s = csr_src[j];
    den += __expf(lrelu(a_src[s] + ad) - m);
  }
#pragma unroll
  for (int off = 32; off; off >>= 1) den += __shfl_xor(den, off, 64);
  float inv = 1.f / den;

  const unsigned int* hrow = (const unsigned int*)hbf;   // 64 uints (=128 bf16) per row
  float accx = 0.f, accy = 0.f;
  int lim = deg < 64 ? deg : 64;
  for (int jj = 0; jj < lim; ++jj) {
    int s = __shfl(sA, jj, 64);
    float wgt = __shfl(preg, jj, 64) * inv;
    unsigned int u = hrow[(size_t)s * 64 + lane];
    float lo = __uint_as_float(u << 16);
    float hi = __uint_as_float(u & 0xffff0000u);
    accx = fmaf(wgt, lo, accx);
    accy = fmaf(wgt, hi, accy);
  }
  for (int j = s0 + 64; j < s1; ++j) {  // rare: deg > 64
    int s = csr_src[j];
    float wgt = __expf(lrelu(a_src[s] + ad) - m) * inv;
    unsigned int u = hrow[(size_t)s * 64 + lane];
    float lo = __uint_as_float(u << 16);
    float hi = __uint_as_float(u & 0xffff0000u);
    accx = fmaf(wgt, lo, accx);
    accy = fmaf(wgt, hi, accy);
  }
  float2 bv = *(const float2*)&bias[2 * lane];
  accx = fmaxf(accx + bv.x, 0.f);
  accy = fmaxf(accy + bv.y, 0.f);
  float2 o; o.x = accx; o.y = accy;
  *(float2*)&outp[(size_t)w * 128 + 2 * lane] = o;
}

// ---------------- BatchNorm stats / finalize ----------------
__global__ __launch_bounds__(256) void bn_stats_k(const float* __restrict__ z, int N,
                                                  float* __restrict__ sums, float* __restrict__ sumsq) {
  __shared__ float ls[256], lq[256];
  int col = threadIdx.x & 63;
  int rg = threadIdx.x >> 6;
  float s = 0.f, q = 0.f;
  for (int r = blockIdx.x * 4 + rg; r < N; r += gridDim.x * 4) {
    float v = z[(size_t)r * 64 + col];
    s += v;
    q = fmaf(v, v, q);
  }
  ls[threadIdx.x] = s;
  lq[threadIdx.x] = q;
  __syncthreads();
  if (threadIdx.x < 64) {
    s = ls[col] + ls[col + 64] + ls[col + 128] + ls[col + 192];
    q = lq[col] + lq[col + 64] + lq[col + 128] + lq[col + 192];
    atomicAdd(&sums[col], s);
    atomicAdd(&sumsq[col], q);
  }
}

__global__ void bn_finalize_k(const float* __restrict__ sums, const float* __restrict__ sumsq,
                              const float* __restrict__ gamma, const float* __restrict__ beta,
                              int N, float* __restrict__ scale, float* __restrict__ shift) {
  int c = threadIdx.x;
  if (c >= 64) return;
  float mean = sums[c] / (float)N;
  float var = sumsq[c] / (float)N - mean * mean;
  float rs = rsqrtf(var + BN_EPS);
  float sc = gamma[c] * rs;
  scale[c] = sc;
  shift[c] = beta[c] - mean * sc;
}

// ---------------- fused BN-apply + ReLU + FC2 + log_softmax (thread per node) ----------------
__global__ __launch_bounds__(256) void fc2_lsm_k(const float* __restrict__ z, const float* __restrict__ scale,
                                                 const float* __restrict__ shift, const float* __restrict__ w,
                                                 const float* __restrict__ b, float* __restrict__ out, int N) {
  int n = blockIdx.x * 256 + threadIdx.x;
  if (n >= N) return;
  float o[40];
#pragma unroll
  for (int c = 0; c < 40; ++c) o[c] = b[c];
  const float* zr = z + (size_t)n * 64;
  for (int k = 0; k < 64; ++k) {
    float v = fmaxf(fmaf(zr[k], scale[k], shift[k]), 0.f);
#pragma unroll
    for (int c = 0; c < 40; ++c) o[c] = fmaf(v, w[k * 40 + c], o[c]);
  }
  float mx = o[0];
#pragma unroll
  for (int c = 1; c < 40; ++c) mx = fmaxf(mx, o[c]);
  float s = 0.f;
#pragma unroll
  for (int c = 0; c < 40; ++c) s += __expf(o[c] - mx);
  float ls = __logf(s);
  float* orow = out + (size_t)n * 40;
#pragma unroll
  for (int c = 0; c < 40; ++c) orow[c] = o[c] - mx - ls;
}

// ---------------- launch ----------------
static inline char* al16(char* p) { return (char*)(((size_t)p + 15) & ~(size_t)15); }

extern "C" void kernel_launch(void* const* d_in, const int* in_sizes, int n_in,
                              void* d_out, int out_size, void* d_ws, size_t ws_size,
                              hipStream_t stream) {
  const float* x     = (const float*)d_in[0];
  const int*   eidx  = (const int*)d_in[1];
  const float* W1s   = (const float*)d_in[2];
  const float* W1d   = (const float*)d_in[3];
  const float* att1s = (const float*)d_in[4];
  const float* att1d = (const float*)d_in[5];
  const float* b1    = (const float*)d_in[6];
  const float* W2s   = (const float*)d_in[7];
  const float* W2d   = (const float*)d_in[8];
  const float* att2s = (const float*)d_in[9];
  const float* att2d = (const float*)d_in[10];
  const float* b2    = (const float*)d_in[11];
  const float* fc1w  = (const float*)d_in[12];
  const float* fc1b  = (const float*)d_in[13];
  const float* gamma = (const float*)d_in[14];
  const float* beta  = (const float*)d_in[15];
  const float* fc2w  = (const float*)d_in[16];
  const float* fc2b  = (const float*)d_in[17];
  float* out = (float*)d_out;

  const int N  = in_sizes[0] / 256;
  const int E  = in_sizes[1] / 2;
  const int ET = E + N;
  const int DIN = 256, H1 = 128;

  // workspace layout (~115 MB)
  char* p = (char*)d_ws;
  float* hB = (float*)p;               p += (size_t)N * 128 * 4;   // fp32 agg output
  float* hF = (float*)p;               p += (size_t)N * 64 * 4;    // fp32 FC1 output
  unsigned short* bhA = (unsigned short*)p; p += (size_t)N * 128 * 2; // bf16 gemm output (gather source)
  int* deg      = (int*)p;     p += (size_t)N * 4;
  int* rowstart = (int*)p;     p += (size_t)(N + 1) * 4;
  int* cursor   = (int*)p;     p += (size_t)N * 4;
  int* csr_src  = (int*)p;     p += (size_t)ET * 4;
  float* a_src  = (float*)p;   p += (size_t)N * 4;
  float* a_dst  = (float*)p;   p += (size_t)N * 4;
  float* wvd1   = (float*)p;   p += 256 * 4;
  float* wvd2   = (float*)p;   p += 128 * 4;
  float* sums   = (float*)p;   p += 64 * 4;
  float* sumsq  = (float*)p;   p += 64 * 4;
  float* scale  = (float*)p;   p += 64 * 4;
  float* shift  = (float*)p;   p += 64 * 4;
  int* bsum     = (int*)p;     p += 256 * 4;
  p = al16(p);
  _Float16* B1h = (_Float16*)p; p += (size_t)256 * 128 * 2;
  _Float16* B1l = (_Float16*)p; p += (size_t)256 * 128 * 2;
  _Float16* B2h = (_Float16*)p; p += (size_t)128 * 128 * 2;
  _Float16* B2l = (_Float16*)p; p += (size_t)128 * 128 * 2;
  _Float16* Bfh = (_Float16*)p; p += (size_t)128 * 64 * 2;
  _Float16* Bfl = (_Float16*)p; p += (size_t)128 * 64 * 2;

  const int* esrc = eidx;
  const int* edst = eidx + E;

  // ---- CSR build (by dst, self-loops appended) ----
  hipMemsetAsync(deg, 0, (size_t)N * 4, stream);
  deg_count_k<<<(ET + 255) / 256, 256, 0, stream>>>(edst, E, N, deg);
  int nb = (N + 1023) / 1024;
  scan1_k<<<nb, 1024, 0, stream>>>(deg, N, rowstart, bsum);
  scan2_k<<<1, 64, 0, stream>>>(bsum, nb);
  scan3_k<<<(N + 255) / 256, 256, 0, stream>>>(rowstart, bsum, N, ET, cursor);
  // 8 range-filtered scatter passes: each write region ~ET/8*4B fits L2, writes merge.
  {
    const int NR = 8;
    int step = (N + NR - 1) / NR;
    for (int r = 0; r < NR; ++r) {
      int d0 = r * step;
      int d1 = d0 + step < N ? d0 + step : N;
      scatter_range_k<<<(ET + 255) / 256, 256, 0, stream>>>(esrc, edst, E, N, d0, d1, cursor, csr_src);
    }
  }

  // ---- one-time B frag pre-splits + a_dst fold vectors ----
  bfrag_k<<<16, 256, 0, stream>>>(W1s, B1h, B1l, 256, 128);
  bfrag_k<<<8, 256, 0, stream>>>(W2s, B2h, B2l, 128, 128);
  bfrag_k<<<4, 256, 0, stream>>>(fc1w, Bfh, Bfl, 128, 64);
  matvec_k<<<64, 256, 0, stream>>>(W1d, att1d, wvd1, 256, 128);   // wvd1 = W1_dst @ att1_dst
  matvec_k<<<32, 256, 0, stream>>>(W2d, att2d, wvd2, 128, 128);

  const int gemm_blocks = (N + 127) / 128;

  // ---- GAT layer 1: gemm writes bf16 h + fused a_src; a_dst via folded matvec ----
  gemm3h_k<128><<<gemm_blocks, 256, 0, stream>>>(x, B1h, B1l, (float*)nullptr, bhA, att1s, a_src,
                                                 N, DIN, (const float*)nullptr);
  matvec_k<<<(N + 3) / 4, 256, 0, stream>>>(x, wvd1, a_dst, N, DIN);
  gat_agg_k<<<(N + 3) / 4, 256, 0, stream>>>(bhA, a_src, a_dst, rowstart, csr_src, b1, hB, N);

  // ---- GAT layer 2 ----
  gemm3h_k<128><<<gemm_blocks, 256, 0, stream>>>(hB, B2h, B2l, (float*)nullptr, bhA, att2s, a_src,
                                                 N, H1, (const float*)nullptr);
  matvec_k<<<(N + 3) / 4, 256, 0, stream>>>(hB, wvd2, a_dst, N, H1);
  gat_agg_k<<<(N + 3) / 4, 256, 0, stream>>>(bhA, a_src, a_dst, rowstart, csr_src, b2, hB, N);

  // ---- FC1 (+bias) -> BN -> fused BN-apply+ReLU+FC2+log_softmax ----
  gemm3h_k<64><<<gemm_blocks, 256, 0, stream>>>(hB, Bfh, Bfl, hF, (unsigned short*)nullptr,
                                                (const float*)nullptr, (float*)nullptr, N, H1, fc1b);
  hipMemsetAsync(sums, 0, 128 * sizeof(float), stream);
  bn_stats_k<<<512, 256, 0, stream>>>(hF, N, sums, sumsq);
  bn_finalize_k<<<1, 64, 0, stream>>>(sums, sumsq, gamma, beta, N, scale, shift);
  fc2_lsm_k<<<(N + 255) / 256, 256, 0, stream>>>(hF, scale, shift, fc2w, fc2b, out, N);
}

// Round 10
// 764.289 us; speedup vs baseline: 1.3706x; 1.1166x over previous
//
#include <hip/hip_runtime.h>
#include <cstddef>

#define LSLOPE 0.2f
#define BN_EPS 1e-5f

__device__ __forceinline__ float lrelu(float x) { return x > 0.f ? x : LSLOPE * x; }

using half4 = __attribute__((ext_vector_type(4))) _Float16;
using half8 = __attribute__((ext_vector_type(8))) _Float16;
using f32x4 = __attribute__((ext_vector_type(4))) float;

struct h2 { _Float16 h, l; };
__device__ __forceinline__ h2 split2h(float x) {
  h2 r;
  r.h = (_Float16)x;
  r.l = (_Float16)(x - (float)r.h);
  return r;
}

__device__ __forceinline__ unsigned short f2bf(float x) {
  unsigned u = __float_as_uint(x);
  unsigned r = (u + 0x7fffu + ((u >> 16) & 1u)) >> 16;
  return (unsigned short)r;
}
__device__ __forceinline__ float bflo(unsigned int u) { return __uint_as_float(u << 16); }
__device__ __forceinline__ float bfhi(unsigned int u) { return __uint_as_float(u & 0xffff0000u); }

// ---------- one-time B pre-split into MFMA-frag order ----------
__global__ void bfrag_k(const float* __restrict__ B, _Float16* __restrict__ bh,
                        _Float16* __restrict__ bl, int K, int M) {
  int t = blockIdx.x * 256 + threadIdx.x;
  int KB = K >> 5;
  int total = (M >> 4) * KB * 64;
  if (t >= total) return;
  int lane = t & 63;
  int ckb  = t >> 6;
  int c  = ckb / KB, kb = ckb % KB;
  int mr = lane & 15, quad = lane >> 4;
  int col = c * 16 + mr;
  size_t obase = (size_t)t * 8;
#pragma unroll
  for (int j = 0; j < 8; ++j) {
    int k = kb * 32 + quad * 8 + j;
    h2 s = split2h(B[(size_t)k * M + col]);
    bh[obase + j] = s.h;
    bl[obase + j] = s.l;
  }
}

// ---------- f16 3-term MFMA GEMM: C[N,M] = A[N,K] @ B[K,M] (+bias), M == MCOLS ----------
template<int MCOLS>
__global__ __launch_bounds__(256) void gemm3h_k(const float* __restrict__ A,
                                                const _Float16* __restrict__ Bh,
                                                const _Float16* __restrict__ Bl,
                                                float* __restrict__ Cf,
                                                unsigned short* __restrict__ Cbf,
                                                const float* __restrict__ attv,
                                                float* __restrict__ asrc,
                                                int N, int K,
                                                const float* __restrict__ bias) {
  constexpr int CT = MCOLS / 16;
  __shared__ __align__(16) _Float16 sAh[128 * 32];
  __shared__ __align__(16) _Float16 sAl[128 * 32];
  const int tid  = threadIdx.x;
  const int row0 = blockIdx.x * 128;
  const int wv   = tid >> 6;
  const int lane = tid & 63;
  const int quad = lane >> 4;
  const int mr   = lane & 15;
  const int KB   = K >> 5;

  f32x4 acc[2][CT];
#pragma unroll
  for (int r = 0; r < 2; ++r)
#pragma unroll
    for (int c = 0; c < CT; ++c) acc[r][c] = (f32x4){0.f, 0.f, 0.f, 0.f};

  for (int kb = 0; kb < KB; ++kb) {
    const int kk = kb << 5;
#pragma unroll
    for (int cc = 0; cc < 4; ++cc) {
      int s = tid + cc * 256;
      int r = s >> 3, kc = (s & 7) << 2;
      float4 v = make_float4(0.f, 0.f, 0.f, 0.f);
      int gr = row0 + r;
      if (gr < N) v = *(const float4*)&A[(size_t)gr * K + kk + kc];
      h2 s0 = split2h(v.x);
      h2 s1 = split2h(v.y);
      h2 s2 = split2h(v.z);
      h2 s3 = split2h(v.w);
      half4 h4, l4;
      h4[0] = s0.h; h4[1] = s1.h; h4[2] = s2.h; h4[3] = s3.h;
      l4[0] = s0.l; l4[1] = s1.l; l4[2] = s2.l; l4[3] = s3.l;
      int off = r * 32 + ((kc + r * 8) & 31);
      *(half4*)&sAh[off] = h4;
      *(half4*)&sAl[off] = l4;
    }
    __syncthreads();

    half8 ah[2], al[2];
#pragma unroll
    for (int r = 0; r < 2; ++r) {
      int row = wv * 32 + r * 16 + mr;
      int off = row * 32 + ((quad + row) & 3) * 8;
      ah[r] = *(const half8*)&sAh[off];
      al[r] = *(const half8*)&sAl[off];
    }
    const _Float16* bb_h = Bh + ((size_t)kb * 64 + lane) * 8;
    const _Float16* bb_l = Bl + ((size_t)kb * 64 + lane) * 8;
    const size_t cstride = (size_t)KB * 512;
#pragma unroll
    for (int c0 = 0; c0 < CT; c0 += 4) {
      half8 bh4[4], bl4[4];
#pragma unroll
      for (int c = 0; c < 4; ++c) {
        size_t o = (size_t)(c0 + c) * cstride;
        bh4[c] = *(const half8*)&bb_h[o];
        bl4[c] = *(const half8*)&bb_l[o];
      }
#pragma unroll
      for (int r = 0; r < 2; ++r)
#pragma unroll
        for (int c = 0; c < 4; ++c) {
          f32x4 a = acc[r][c0 + c];
          a = __builtin_amdgcn_mfma_f32_16x16x32_f16(al[r], bh4[c], a, 0, 0, 0);
          a = __builtin_amdgcn_mfma_f32_16x16x32_f16(ah[r], bl4[c], a, 0, 0, 0);
          a = __builtin_amdgcn_mfma_f32_16x16x32_f16(ah[r], bh4[c], a, 0, 0, 0);
          acc[r][c0 + c] = a;
        }
    }
    __syncthreads();
  }

  // epilogue: D col = lane&15, row = (lane>>4)*4 + reg  [m89/m91-verified]
  float pa[2][4];
#pragma unroll
  for (int r = 0; r < 2; ++r)
#pragma unroll
    for (int q = 0; q < 4; ++q) pa[r][q] = 0.f;

#pragma unroll
  for (int r = 0; r < 2; ++r)
#pragma unroll
    for (int c = 0; c < CT; ++c) {
      float av = attv ? attv[c * 16 + mr] : 0.f;
#pragma unroll
      for (int q = 0; q < 4; ++q) {
        int grow = row0 + wv * 32 + r * 16 + quad * 4 + q;
        float val = acc[r][c][q];
        if (bias) val += bias[c * 16 + mr];
        if (grow < N) {
          int gcol = c * 16 + mr;
          if (Cf)  Cf[(size_t)grow * MCOLS + gcol] = val;
          if (Cbf) Cbf[(size_t)grow * 128 + gcol] = f2bf(val);
        }
        if (attv) pa[r][q] = fmaf(val, av, pa[r][q]);
      }
    }
  if (attv) {
#pragma unroll
    for (int r = 0; r < 2; ++r)
#pragma unroll
      for (int q = 0; q < 4; ++q) {
        float p2 = pa[r][q];
        p2 += __shfl_xor(p2, 1, 64);
        p2 += __shfl_xor(p2, 2, 64);
        p2 += __shfl_xor(p2, 4, 64);
        p2 += __shfl_xor(p2, 8, 64);
        int grow = row0 + wv * 32 + r * 16 + quad * 4 + q;
        if (mr == 0 && grow < N) asrc[grow] = p2;
      }
  }
}

// ---------------- row-wise matvec: out[r] = A[r,:] . v (one wave per row) ----------------
__global__ __launch_bounds__(256) void matvec_k(const float* __restrict__ A, const float* __restrict__ v,
                                                float* __restrict__ out, int R, int K) {
  int w = (blockIdx.x * blockDim.x + threadIdx.x) >> 6;
  int lane = threadIdx.x & 63;
  if (w >= R) return;
  const float* row = A + (size_t)w * K;
  float s = 0.f;
  for (int k = lane; k < K; k += 64) s = fmaf(row[k], v[k], s);
#pragma unroll
  for (int off = 32; off; off >>= 1) s += __shfl_xor(s, off, 64);
  if (lane == 0) out[w] = s;
}

// ---------------- CSR build ----------------
__global__ void deg_count_k(const int* __restrict__ edst, int E, int N, int* __restrict__ deg) {
  int i = blockIdx.x * 256 + threadIdx.x;
  if (i >= E + N) return;
  int d = (i < E) ? edst[i] : (i - E);
  atomicAdd(&deg[d], 1);
}

__global__ __launch_bounds__(1024) void scan1_k(const int* __restrict__ deg, int n,
                                                int* __restrict__ ex, int* __restrict__ bsum) {
  __shared__ int sm[1024];
  int t = threadIdx.x;
  int idx = blockIdx.x * 1024 + t;
  int v = (idx < n) ? deg[idx] : 0;
  sm[t] = v;
  __syncthreads();
  for (int off = 1; off < 1024; off <<= 1) {
    int tv = (t >= off) ? sm[t - off] : 0;
    __syncthreads();
    sm[t] += tv;
    __syncthreads();
  }
  if (idx < n) ex[idx] = sm[t] - v;
  if (t == 1023) bsum[blockIdx.x] = sm[t];
}

__global__ void scan2_k(int* __restrict__ bsum, int nb) {
  if (threadIdx.x == 0 && blockIdx.x == 0) {
    int run = 0;
    for (int b = 0; b < nb; ++b) { int x = bsum[b]; bsum[b] = run; run += x; }
  }
}

__global__ void scan3_k(int* __restrict__ ex, const int* __restrict__ bsum, int n, int total,
                        int* __restrict__ cursor) {
  int idx = blockIdx.x * 256 + threadIdx.x;
  if (idx < n) {
    int v = ex[idx] + bsum[idx >> 10];
    ex[idx] = v;
    cursor[idx] = v;
  }
  if (idx == 0) ex[n] = total;
}

// range-filtered scatter: only edges with dst in [d0,d1); write region fits L2, merges.
__global__ void scatter_range_k(const int* __restrict__ esrc, const int* __restrict__ edst,
                                int E, int N, int d0, int d1,
                                int* __restrict__ cursor, int* __restrict__ csr_src) {
  int i = blockIdx.x * 256 + threadIdx.x;
  if (i >= E + N) return;
  int d = (i < E) ? edst[i] : (i - E);
  if (d < d0 || d >= d1) return;
  int s = (i < E) ? esrc[i] : d;
  int pos = atomicAdd(&cursor[d], 1);
  csr_src[pos] = s;
}

// ---------------- GAT aggregation: wave/dst; quarter-wave uint4 gather, UNIFORM exec ----------------
__global__ __launch_bounds__(256) void gat_agg_k(const unsigned short* __restrict__ hbf,
                                                 const float* __restrict__ a_src,
                                                 const float* __restrict__ a_dst, const int* __restrict__ rowstart,
                                                 const int* __restrict__ csr_src, const float* __restrict__ bias,
                                                 float* __restrict__ outp, int N) {
  int w = (blockIdx.x * blockDim.x + threadIdx.x) >> 6;
  int lane = threadIdx.x & 63;
  if (w >= N) return;
  int s0 = rowstart[w];
  int s1 = rowstart[w + 1];
  int deg = s1 - s0;
  float ad = a_dst[w];

  // first (<=64) edges resident in registers; lanes >= deg hold sA=0, preg=0
  int sA = 0;
  float eA = -3.0e38f;
  if (lane < deg) {
    sA = csr_src[s0 + lane];
    eA = lrelu(a_src[sA] + ad);
  }
  float m = eA;
  for (int j = s0 + 64 + lane; j < s1; j += 64) {
    int s = csr_src[j];
    m = fmaxf(m, lrelu(a_src[s] + ad));
  }
#pragma unroll
  for (int off = 32; off; off >>= 1) m = fmaxf(m, __shfl_xor(m, off, 64));

  float preg = (lane < deg) ? __expf(eA - m) : 0.f;
  float den = preg;
  for (int j = s0 + 64 + lane; j < s1; j += 64) {
    int s = csr_src[j];
    den += __expf(lrelu(a_src[s] + ad) - m);
  }
#pragma unroll
  for (int off = 32; off; off >>= 1) den += __shfl_xor(den, off, 64);
  float inv = 1.f / den;

  // gather: quarter q takes edge jj+q; lane sl loads uint4 = 8 bf16 (cols 8*sl..8*sl+7).
  // Loop bound padded to multiple of 4 (<=64): ALL 64 lanes run every iteration, so every
  // __shfl executes with full exec (divergent-exec shfl broke rounds 2/9). Out-of-range
  // edges (e in [deg,lim4)) have preg=0 -> wgt=0 -> contribute nothing.
  const int q  = lane >> 4;
  const int sl = lane & 15;
  const uint4* hrow4 = (const uint4*)hbf;    // 16 uint4 per 128-col row
  float acc[8];
#pragma unroll
  for (int i = 0; i < 8; ++i) acc[i] = 0.f;

  int lim  = deg < 64 ? deg : 64;
  int lim4 = (lim + 3) & ~3;                 // uniform, <= 64
  for (int jj = 0; jj < lim4; jj += 4) {
    int e = jj + q;                          // e <= lim4-1 <= 63 always
    int s = __shfl(sA, e, 64);
    float wgt = __shfl(preg, e, 64) * inv;
    uint4 u = hrow4[(size_t)s * 16 + sl];
    acc[0] = fmaf(wgt, bflo(u.x), acc[0]);
    acc[1] = fmaf(wgt, bfhi(u.x), acc[1]);
    acc[2] = fmaf(wgt, bflo(u.y), acc[2]);
    acc[3] = fmaf(wgt, bfhi(u.y), acc[3]);
    acc[4] = fmaf(wgt, bflo(u.z), acc[4]);
    acc[5] = fmaf(wgt, bfhi(u.z), acc[5]);
    acc[6] = fmaf(wgt, bflo(u.w), acc[6]);
    acc[7] = fmaf(wgt, bfhi(u.w), acc[7]);
  }
  // rare deg>64 tail: divergent but shfl-free (plain exec masking is safe)
  for (int j = s0 + 64 + q; j < s1; j += 4) {
    int s = csr_src[j];
    float wgt = __expf(lrelu(a_src[s] + ad) - m) * inv;
    uint4 u = hrow4[(size_t)s * 16 + sl];
    acc[0] = fmaf(wgt, bflo(u.x), acc[0]);
    acc[1] = fmaf(wgt, bfhi(u.x), acc[1]);
    acc[2] = fmaf(wgt, bflo(u.y), acc[2]);
    acc[3] = fmaf(wgt, bfhi(u.y), acc[3]);
    acc[4] = fmaf(wgt, bflo(u.z), acc[4]);
    acc[5] = fmaf(wgt, bfhi(u.z), acc[5]);
    acc[6] = fmaf(wgt, bflo(u.w), acc[6]);
    acc[7] = fmaf(wgt, bfhi(u.w), acc[7]);
  }
  // combine quarter-wave partials (cols identical across q at fixed sl); full exec here
#pragma unroll
  for (int i = 0; i < 8; ++i) {
    acc[i] += __shfl_xor(acc[i], 16, 64);
    acc[i] += __shfl_xor(acc[i], 32, 64);
  }
  if (q == 0) {
    float4 b0 = *(const float4*)&bias[8 * sl];
    float4 b1 = *(const float4*)&bias[8 * sl + 4];
    float4 o0, o1;
    o0.x = fmaxf(acc[0] + b0.x, 0.f);
    o0.y = fmaxf(acc[1] + b0.y, 0.f);
    o0.z = fmaxf(acc[2] + b0.z, 0.f);
    o0.w = fmaxf(acc[3] + b0.w, 0.f);
    o1.x = fmaxf(acc[4] + b1.x, 0.f);
    o1.y = fmaxf(acc[5] + b1.y, 0.f);
    o1.z = fmaxf(acc[6] + b1.z, 0.f);
    o1.w = fmaxf(acc[7] + b1.w, 0.f);
    float* orow = outp + (size_t)w * 128 + 8 * sl;
    *(float4*)orow = o0;
    *(float4*)(orow + 4) = o1;
  }
}

// ---------------- BatchNorm stats / finalize ----------------
__global__ __launch_bounds__(256) void bn_stats_k(const float* __restrict__ z, int N,
                                                  float* __restrict__ sums, float* __restrict__ sumsq) {
  __shared__ float ls[256], lq[256];
  int col = threadIdx.x & 63;
  int rg = threadIdx.x >> 6;
  float s = 0.f, q = 0.f;
  for (int r = blockIdx.x * 4 + rg; r < N; r += gridDim.x * 4) {
    float v = z[(size_t)r * 64 + col];
    s += v;
    q = fmaf(v, v, q);
  }
  ls[threadIdx.x] = s;
  lq[threadIdx.x] = q;
  __syncthreads();
  if (threadIdx.x < 64) {
    s = ls[col] + ls[col + 64] + ls[col + 128] + ls[col + 192];
    q = lq[col] + lq[col + 64] + lq[col + 128] + lq[col + 192];
    atomicAdd(&sums[col], s);
    atomicAdd(&sumsq[col], q);
  }
}

__global__ void bn_finalize_k(const float* __restrict__ sums, const float* __restrict__ sumsq,
                              const float* __restrict__ gamma, const float* __restrict__ beta,
                              int N, float* __restrict__ scale, float* __restrict__ shift) {
  int c = threadIdx.x;
  if (c >= 64) return;
  float mean = sums[c] / (float)N;
  float var = sumsq[c] / (float)N - mean * mean;
  float rs = rsqrtf(var + BN_EPS);
  float sc = gamma[c] * rs;
  scale[c] = sc;
  shift[c] = beta[c] - mean * sc;
}

// ---------------- fused BN-apply + ReLU + FC2 + log_softmax (thread per node) ----------------
__global__ __launch_bounds__(256) void fc2_lsm_k(const float* __restrict__ z, const float* __restrict__ scale,
                                                 const float* __restrict__ shift, const float* __restrict__ w,
                                                 const float* __restrict__ b, float* __restrict__ out, int N) {
  int n = blockIdx.x * 256 + threadIdx.x;
  if (n >= N) return;
  float o[40];
#pragma unroll
  for (int c = 0; c < 40; ++c) o[c] = b[c];
  const float* zr = z + (size_t)n * 64;
  for (int k = 0; k < 64; ++k) {
    float v = fmaxf(fmaf(zr[k], scale[k], shift[k]), 0.f);
#pragma unroll
    for (int c = 0; c < 40; ++c) o[c] = fmaf(v, w[k * 40 + c], o[c]);
  }
  float mx = o[0];
#pragma unroll
  for (int c = 1; c < 40; ++c) mx = fmaxf(mx, o[c]);
  float s = 0.f;
#pragma unroll
  for (int c = 0; c < 40; ++c) s += __expf(o[c] - mx);
  float ls = __logf(s);
  float* orow = out + (size_t)n * 40;
#pragma unroll
  for (int c = 0; c < 40; ++c) orow[c] = o[c] - mx - ls;
}

// ---------------- launch ----------------
static inline char* al16(char* p) { return (char*)(((size_t)p + 15) & ~(size_t)15); }

extern "C" void kernel_launch(void* const* d_in, const int* in_sizes, int n_in,
                              void* d_out, int out_size, void* d_ws, size_t ws_size,
                              hipStream_t stream) {
  const float* x     = (const float*)d_in[0];
  const int*   eidx  = (const int*)d_in[1];
  const float* W1s   = (const float*)d_in[2];
  const float* W1d   = (const float*)d_in[3];
  const float* att1s = (const float*)d_in[4];
  const float* att1d = (const float*)d_in[5];
  const float* b1    = (const float*)d_in[6];
  const float* W2s   = (const float*)d_in[7];
  const float* W2d   = (const float*)d_in[8];
  const float* att2s = (const float*)d_in[9];
  const float* att2d = (const float*)d_in[10];
  const float* b2    = (const float*)d_in[11];
  const float* fc1w  = (const float*)d_in[12];
  const float* fc1b  = (const float*)d_in[13];
  const float* gamma = (const float*)d_in[14];
  const float* beta  = (const float*)d_in[15];
  const float* fc2w  = (const float*)d_in[16];
  const float* fc2b  = (const float*)d_in[17];
  float* out = (float*)d_out;

  const int N  = in_sizes[0] / 256;
  const int E  = in_sizes[1] / 2;
  const int ET = E + N;
  const int DIN = 256, H1 = 128;

  // workspace layout (~115 MB)
  char* p = (char*)d_ws;
  float* hB = (float*)p;               p += (size_t)N * 128 * 4;   // fp32 agg output
  float* hF = (float*)p;               p += (size_t)N * 64 * 4;    // fp32 FC1 output
  unsigned short* bhA = (unsigned short*)p; p += (size_t)N * 128 * 2; // bf16 gemm output (gather source)
  int* deg      = (int*)p;     p += (size_t)N * 4;
  int* rowstart = (int*)p;     p += (size_t)(N + 1) * 4;
  int* cursor   = (int*)p;     p += (size_t)N * 4;
  int* csr_src  = (int*)p;     p += (size_t)ET * 4;
  float* a_src  = (float*)p;   p += (size_t)N * 4;
  float* a_dst  = (float*)p;   p += (size_t)N * 4;
  float* wvd1   = (float*)p;   p += 256 * 4;
  float* wvd2   = (float*)p;   p += 128 * 4;
  float* sums   = (float*)p;   p += 64 * 4;
  float* sumsq  = (float*)p;   p += 64 * 4;
  float* scale  = (float*)p;   p += 64 * 4;
  float* shift  = (float*)p;   p += 64 * 4;
  int* bsum     = (int*)p;     p += 256 * 4;
  p = al16(p);
  _Float16* B1h = (_Float16*)p; p += (size_t)256 * 128 * 2;
  _Float16* B1l = (_Float16*)p; p += (size_t)256 * 128 * 2;
  _Float16* B2h = (_Float16*)p; p += (size_t)128 * 128 * 2;
  _Float16* B2l = (_Float16*)p; p += (size_t)128 * 128 * 2;
  _Float16* Bfh = (_Float16*)p; p += (size_t)128 * 64 * 2;
  _Float16* Bfl = (_Float16*)p; p += (size_t)128 * 64 * 2;

  const int* esrc = eidx;
  const int* edst = eidx + E;

  // ---- CSR build (by dst, self-loops appended) ----
  hipMemsetAsync(deg, 0, (size_t)N * 4, stream);
  deg_count_k<<<(ET + 255) / 256, 256, 0, stream>>>(edst, E, N, deg);
  int nb = (N + 1023) / 1024;
  scan1_k<<<nb, 1024, 0, stream>>>(deg, N, rowstart, bsum);
  scan2_k<<<1, 64, 0, stream>>>(bsum, nb);
  scan3_k<<<(N + 255) / 256, 256, 0, stream>>>(rowstart, bsum, N, ET, cursor);
  {
    const int NR = 8;
    int step = (N + NR - 1) / NR;
    for (int r = 0; r < NR; ++r) {
      int d0 = r * step;
      int d1 = d0 + step < N ? d0 + step : N;
      scatter_range_k<<<(ET + 255) / 256, 256, 0, stream>>>(esrc, edst, E, N, d0, d1, cursor, csr_src);
    }
  }

  // ---- one-time B frag pre-splits + a_dst fold vectors ----
  bfrag_k<<<16, 256, 0, stream>>>(W1s, B1h, B1l, 256, 128);
  bfrag_k<<<8, 256, 0, stream>>>(W2s, B2h, B2l, 128, 128);
  bfrag_k<<<4, 256, 0, stream>>>(fc1w, Bfh, Bfl, 128, 64);
  matvec_k<<<64, 256, 0, stream>>>(W1d, att1d, wvd1, 256, 128);   // wvd1 = W1_dst @ att1_dst
  matvec_k<<<32, 256, 0, stream>>>(W2d, att2d, wvd2, 128, 128);

  const int gemm_blocks = (N + 127) / 128;

  // ---- GAT layer 1: gemm writes bf16 h + fused a_src; a_dst via folded matvec ----
  gemm3h_k<128><<<gemm_blocks, 256, 0, stream>>>(x, B1h, B1l, (float*)nullptr, bhA, att1s, a_src,
                                                 N, DIN, (const float*)nullptr);
  matvec_k<<<(N + 3) / 4, 256, 0, stream>>>(x, wvd1, a_dst, N, DIN);
  gat_agg_k<<<(N + 3) / 4, 256, 0, stream>>>(bhA, a_src, a_dst, rowstart, csr_src, b1, hB, N);

  // ---- GAT layer 2 ----
  gemm3h_k<128><<<gemm_blocks, 256, 0, stream>>>(hB, B2h, B2l, (float*)nullptr, bhA, att2s, a_src,
                                                 N, H1, (const float*)nullptr);
  matvec_k<<<(N + 3) / 4, 256, 0, stream>>>(hB, wvd2, a_dst, N, H1);
  gat_agg_k<<<(N + 3) / 4, 256, 0, stream>>>(bhA, a_src, a_dst, rowstart, csr_src, b2, hB, N);

  // ---- FC1 (+bias) -> BN -> fused BN-apply+ReLU+FC2+log_softmax ----
  gemm3h_k<64><<<gemm_blocks, 256, 0, stream>>>(hB, Bfh, Bfl, hF, (unsigned short*)nullptr,
                                                (const float*)nullptr, (float*)nullptr, N, H1, fc1b);
  hipMemsetAsync(sums, 0, 128 * sizeof(float), stream);
  bn_stats_k<<<512, 256, 0, stream>>>(hF, N, sums, sumsq);
  bn_finalize_k<<<1, 64, 0, stream>>>(sums, sumsq, gamma, beta, N, scale, shift);
  fc2_lsm_k<<<(N + 255) / 256, 256, 0, stream>>>(hF, scale, shift, fc2w, fc2b, out, N);
}

// Round 11
// 763.923 us; speedup vs baseline: 1.3713x; 1.0005x over previous
//
#include <hip/hip_runtime.h>
#include <cstddef>

#define LSLOPE 0.2f
#define BN_EPS 1e-5f

__device__ __forceinline__ float lrelu(float x) { return x > 0.f ? x : LSLOPE * x; }

using half4 = __attribute__((ext_vector_type(4))) _Float16;
using half8 = __attribute__((ext_vector_type(8))) _Float16;
using f32x4 = __attribute__((ext_vector_type(4))) float;

struct h2 { _Float16 h, l; };
__device__ __forceinline__ h2 split2h(float x) {
  h2 r;
  r.h = (_Float16)x;
  r.l = (_Float16)(x - (float)r.h);
  return r;
}

__device__ __forceinline__ unsigned short f2bf(float x) {
  unsigned u = __float_as_uint(x);
  unsigned r = (u + 0x7fffu + ((u >> 16) & 1u)) >> 16;
  return (unsigned short)r;
}
__device__ __forceinline__ float bflo(unsigned int u) { return __uint_as_float(u << 16); }
__device__ __forceinline__ float bfhi(unsigned int u) { return __uint_as_float(u & 0xffff0000u); }

// ---------- one-time B pre-split into MFMA-frag order ----------
__global__ void bfrag_k(const float* __restrict__ B, _Float16* __restrict__ bh,
                        _Float16* __restrict__ bl, int K, int M) {
  int t = blockIdx.x * 256 + threadIdx.x;
  int KB = K >> 5;
  int total = (M >> 4) * KB * 64;
  if (t >= total) return;
  int lane = t & 63;
  int ckb  = t >> 6;
  int c  = ckb / KB, kb = ckb % KB;
  int mr = lane & 15, quad = lane >> 4;
  int col = c * 16 + mr;
  size_t obase = (size_t)t * 8;
#pragma unroll
  for (int j = 0; j < 8; ++j) {
    int k = kb * 32 + quad * 8 + j;
    h2 s = split2h(B[(size_t)k * M + col]);
    bh[obase + j] = s.h;
    bl[obase + j] = s.l;
  }
}

// ---------- f16 3-term MFMA GEMM, fp32 A, double-buffered LDS + reg prefetch ----------
// C = Ah*Bh + Ah*Bl + Al*Bh. Outputs: Cf fp32 / Cbf bf16 / asrc = C_row.attv
template<int MCOLS>
__global__ __launch_bounds__(256) void gemm3h_k(const float* __restrict__ A,
                                                const _Float16* __restrict__ Bh,
                                                const _Float16* __restrict__ Bl,
                                                float* __restrict__ Cf,
                                                unsigned short* __restrict__ Cbf,
                                                const float* __restrict__ attv,
                                                float* __restrict__ asrc,
                                                int N, int K,
                                                const float* __restrict__ bias) {
  constexpr int CT = MCOLS / 16;
  __shared__ __align__(16) _Float16 sAh[2][128 * 32];
  __shared__ __align__(16) _Float16 sAl[2][128 * 32];
  const int tid  = threadIdx.x;
  const int row0 = blockIdx.x * 128;
  const int wv   = tid >> 6;
  const int lane = tid & 63;
  const int quad = lane >> 4;
  const int mr   = lane & 15;
  const int KB   = K >> 5;

  // staging slots: s = tid + cc*256; row = s>>3, kcol = (s&7)*4
  int srow[4], skc[4], soff[4];
  bool sok[4];
#pragma unroll
  for (int cc = 0; cc < 4; ++cc) {
    int s = tid + cc * 256;
    srow[cc] = s >> 3;
    skc[cc]  = (s & 7) << 2;
    soff[cc] = srow[cc] * 32 + ((skc[cc] + srow[cc] * 8) & 31);
    sok[cc]  = (row0 + srow[cc]) < N;
  }

  f32x4 acc[2][CT];
#pragma unroll
  for (int r = 0; r < 2; ++r)
#pragma unroll
    for (int c = 0; c < CT; ++c) acc[r][c] = (f32x4){0.f, 0.f, 0.f, 0.f};

  float4 pf[4];
  // prologue: tile 0
#pragma unroll
  for (int cc = 0; cc < 4; ++cc)
    pf[cc] = sok[cc] ? *(const float4*)&A[(size_t)(row0 + srow[cc]) * K + skc[cc]]
                     : make_float4(0.f, 0.f, 0.f, 0.f);
#pragma unroll
  for (int cc = 0; cc < 4; ++cc) {
    h2 s0 = split2h(pf[cc].x), s1 = split2h(pf[cc].y), s2 = split2h(pf[cc].z), s3 = split2h(pf[cc].w);
    half4 h4, l4;
    h4[0] = s0.h; h4[1] = s1.h; h4[2] = s2.h; h4[3] = s3.h;
    l4[0] = s0.l; l4[1] = s1.l; l4[2] = s2.l; l4[3] = s3.l;
    *(half4*)&sAh[0][soff[cc]] = h4;
    *(half4*)&sAl[0][soff[cc]] = l4;
  }
  __syncthreads();

  for (int kb = 0; kb < KB; ++kb) {
    const int cur = kb & 1, nxt = cur ^ 1;
    if (kb + 1 < KB) {
      const int kk = (kb + 1) << 5;
#pragma unroll
      for (int cc = 0; cc < 4; ++cc)
        pf[cc] = sok[cc] ? *(const float4*)&A[(size_t)(row0 + srow[cc]) * K + kk + skc[cc]]
                         : make_float4(0.f, 0.f, 0.f, 0.f);
    }

    half8 ah[2], al[2];
#pragma unroll
    for (int r = 0; r < 2; ++r) {
      int row = wv * 32 + r * 16 + mr;
      int off = row * 32 + ((quad + row) & 3) * 8;
      ah[r] = *(const half8*)&sAh[cur][off];
      al[r] = *(const half8*)&sAl[cur][off];
    }
    const _Float16* bb_h = Bh + ((size_t)kb * 64 + lane) * 8;
    const _Float16* bb_l = Bl + ((size_t)kb * 64 + lane) * 8;
    const size_t cstride = (size_t)KB * 512;
#pragma unroll
    for (int c0 = 0; c0 < CT; c0 += 4) {
      half8 bh4[4], bl4[4];
#pragma unroll
      for (int c = 0; c < 4; ++c) {
        size_t o = (size_t)(c0 + c) * cstride;
        bh4[c] = *(const half8*)&bb_h[o];
        bl4[c] = *(const half8*)&bb_l[o];
      }
#pragma unroll
      for (int r = 0; r < 2; ++r)
#pragma unroll
        for (int c = 0; c < 4; ++c) {
          f32x4 a = acc[r][c0 + c];
          a = __builtin_amdgcn_mfma_f32_16x16x32_f16(al[r], bh4[c], a, 0, 0, 0);
          a = __builtin_amdgcn_mfma_f32_16x16x32_f16(ah[r], bl4[c], a, 0, 0, 0);
          a = __builtin_amdgcn_mfma_f32_16x16x32_f16(ah[r], bh4[c], a, 0, 0, 0);
          acc[r][c0 + c] = a;
        }
    }
    if (kb + 1 < KB) {
#pragma unroll
      for (int cc = 0; cc < 4; ++cc) {
        h2 s0 = split2h(pf[cc].x), s1 = split2h(pf[cc].y), s2 = split2h(pf[cc].z), s3 = split2h(pf[cc].w);
        half4 h4, l4;
        h4[0] = s0.h; h4[1] = s1.h; h4[2] = s2.h; h4[3] = s3.h;
        l4[0] = s0.l; l4[1] = s1.l; l4[2] = s2.l; l4[3] = s3.l;
        *(half4*)&sAh[nxt][soff[cc]] = h4;
        *(half4*)&sAl[nxt][soff[cc]] = l4;
      }
    }
    __syncthreads();
  }

  // epilogue: D col = lane&15, row = (lane>>4)*4 + reg  [m89/m91-verified]
  float pa[2][4];
#pragma unroll
  for (int r = 0; r < 2; ++r)
#pragma unroll
    for (int q = 0; q < 4; ++q) pa[r][q] = 0.f;

#pragma unroll
  for (int r = 0; r < 2; ++r)
#pragma unroll
    for (int c = 0; c < CT; ++c) {
      float av = attv ? attv[c * 16 + mr] : 0.f;
#pragma unroll
      for (int q = 0; q < 4; ++q) {
        int grow = row0 + wv * 32 + r * 16 + quad * 4 + q;
        float val = acc[r][c][q];
        if (bias) val += bias[c * 16 + mr];
        if (grow < N) {
          int gcol = c * 16 + mr;
          if (Cf)  Cf[(size_t)grow * MCOLS + gcol] = val;
          if (Cbf) Cbf[(size_t)grow * 128 + gcol] = f2bf(val);
        }
        if (attv) pa[r][q] = fmaf(val, av, pa[r][q]);
      }
    }
  if (attv) {
#pragma unroll
    for (int r = 0; r < 2; ++r)
#pragma unroll
      for (int q = 0; q < 4; ++q) {
        float p2 = pa[r][q];
        p2 += __shfl_xor(p2, 1, 64);
        p2 += __shfl_xor(p2, 2, 64);
        p2 += __shfl_xor(p2, 4, 64);
        p2 += __shfl_xor(p2, 8, 64);
        int grow = row0 + wv * 32 + r * 16 + quad * 4 + q;
        if (mr == 0 && grow < N) asrc[grow] = p2;
      }
  }
}

// ---------- f16 3-term MFMA GEMM, PRE-SPLIT f16 A (h/l pair), double-buffered ----------
template<int MCOLS>
__global__ __launch_bounds__(256) void gemm3p_k(const _Float16* __restrict__ Ah,
                                                const _Float16* __restrict__ Al,
                                                const _Float16* __restrict__ Bh,
                                                const _Float16* __restrict__ Bl,
                                                float* __restrict__ Cf,
                                                unsigned short* __restrict__ Cbf,
                                                const float* __restrict__ attv,
                                                float* __restrict__ asrc,
                                                int N, int K,
                                                const float* __restrict__ bias) {
  constexpr int CT = MCOLS / 16;
  __shared__ __align__(16) _Float16 sAh[2][128 * 32];
  __shared__ __align__(16) _Float16 sAl[2][128 * 32];
  const int tid  = threadIdx.x;
  const int row0 = blockIdx.x * 128;
  const int wv   = tid >> 6;
  const int lane = tid & 63;
  const int quad = lane >> 4;
  const int mr   = lane & 15;
  const int KB   = K >> 5;

  // staging slots: s = tid + cc*256; row = s>>2, k8 = (s&3)*8  (8-f16 = 16B chunks)
  int srow[2], sk8[2], soff[2];
  bool sok[2];
#pragma unroll
  for (int cc = 0; cc < 2; ++cc) {
    int s = tid + cc * 256;
    srow[cc] = s >> 2;
    sk8[cc]  = (s & 3) << 3;
    soff[cc] = srow[cc] * 32 + ((sk8[cc] + srow[cc] * 8) & 31);
    sok[cc]  = (row0 + srow[cc]) < N;
  }

  f32x4 acc[2][CT];
#pragma unroll
  for (int r = 0; r < 2; ++r)
#pragma unroll
    for (int c = 0; c < CT; ++c) acc[r][c] = (f32x4){0.f, 0.f, 0.f, 0.f};

  uint4 ph[2], pl[2];
  const uint4 z4 = make_uint4(0u, 0u, 0u, 0u);
#pragma unroll
  for (int cc = 0; cc < 2; ++cc) {
    size_t go = (size_t)(row0 + srow[cc]) * K + sk8[cc];
    ph[cc] = sok[cc] ? *(const uint4*)&Ah[go] : z4;
    pl[cc] = sok[cc] ? *(const uint4*)&Al[go] : z4;
  }
#pragma unroll
  for (int cc = 0; cc < 2; ++cc) {
    *(uint4*)&sAh[0][soff[cc]] = ph[cc];
    *(uint4*)&sAl[0][soff[cc]] = pl[cc];
  }
  __syncthreads();

  for (int kb = 0; kb < KB; ++kb) {
    const int cur = kb & 1, nxt = cur ^ 1;
    if (kb + 1 < KB) {
      const int kk = (kb + 1) << 5;
#pragma unroll
      for (int cc = 0; cc < 2; ++cc) {
        size_t go = (size_t)(row0 + srow[cc]) * K + kk + sk8[cc];
        ph[cc] = sok[cc] ? *(const uint4*)&Ah[go] : z4;
        pl[cc] = sok[cc] ? *(const uint4*)&Al[go] : z4;
      }
    }

    half8 ah[2], al[2];
#pragma unroll
    for (int r = 0; r < 2; ++r) {
      int row = wv * 32 + r * 16 + mr;
      int off = row * 32 + ((quad + row) & 3) * 8;
      ah[r] = *(const half8*)&sAh[cur][off];
      al[r] = *(const half8*)&sAl[cur][off];
    }
    const _Float16* bb_h = Bh + ((size_t)kb * 64 + lane) * 8;
    const _Float16* bb_l = Bl + ((size_t)kb * 64 + lane) * 8;
    const size_t cstride = (size_t)KB * 512;
#pragma unroll
    for (int c0 = 0; c0 < CT; c0 += 4) {
      half8 bh4[4], bl4[4];
#pragma unroll
      for (int c = 0; c < 4; ++c) {
        size_t o = (size_t)(c0 + c) * cstride;
        bh4[c] = *(const half8*)&bb_h[o];
        bl4[c] = *(const half8*)&bb_l[o];
      }
#pragma unroll
      for (int r = 0; r < 2; ++r)
#pragma unroll
        for (int c = 0; c < 4; ++c) {
          f32x4 a = acc[r][c0 + c];
          a = __builtin_amdgcn_mfma_f32_16x16x32_f16(al[r], bh4[c], a, 0, 0, 0);
          a = __builtin_amdgcn_mfma_f32_16x16x32_f16(ah[r], bl4[c], a, 0, 0, 0);
          a = __builtin_amdgcn_mfma_f32_16x16x32_f16(ah[r], bh4[c], a, 0, 0, 0);
          acc[r][c0 + c] = a;
        }
    }
    if (kb + 1 < KB) {
#pragma unroll
      for (int cc = 0; cc < 2; ++cc) {
        *(uint4*)&sAh[nxt][soff[cc]] = ph[cc];
        *(uint4*)&sAl[nxt][soff[cc]] = pl[cc];
      }
    }
    __syncthreads();
  }

  // epilogue (same layout)
  float pa[2][4];
#pragma unroll
  for (int r = 0; r < 2; ++r)
#pragma unroll
    for (int q = 0; q < 4; ++q) pa[r][q] = 0.f;

#pragma unroll
  for (int r = 0; r < 2; ++r)
#pragma unroll
    for (int c = 0; c < CT; ++c) {
      float av = attv ? attv[c * 16 + mr] : 0.f;
#pragma unroll
      for (int q = 0; q < 4; ++q) {
        int grow = row0 + wv * 32 + r * 16 + quad * 4 + q;
        float val = acc[r][c][q];
        if (bias) val += bias[c * 16 + mr];
        if (grow < N) {
          int gcol = c * 16 + mr;
          if (Cf)  Cf[(size_t)grow * MCOLS + gcol] = val;
          if (Cbf) Cbf[(size_t)grow * 128 + gcol] = f2bf(val);
        }
        if (attv) pa[r][q] = fmaf(val, av, pa[r][q]);
      }
    }
  if (attv) {
#pragma unroll
    for (int r = 0; r < 2; ++r)
#pragma unroll
      for (int q = 0; q < 4; ++q) {
        float p2 = pa[r][q];
        p2 += __shfl_xor(p2, 1, 64);
        p2 += __shfl_xor(p2, 2, 64);
        p2 += __shfl_xor(p2, 4, 64);
        p2 += __shfl_xor(p2, 8, 64);
        int grow = row0 + wv * 32 + r * 16 + quad * 4 + q;
        if (mr == 0 && grow < N) asrc[grow] = p2;
      }
  }
}

// ---------------- row-wise matvec: out[r] = A[r,:] . v (one wave per row) ----------------
__global__ __launch_bounds__(256) void matvec_k(const float* __restrict__ A, const float* __restrict__ v,
                                                float* __restrict__ out, int R, int K) {
  int w = (blockIdx.x * blockDim.x + threadIdx.x) >> 6;
  int lane = threadIdx.x & 63;
  if (w >= R) return;
  const float* row = A + (size_t)w * K;
  float s = 0.f;
  for (int k = lane; k < K; k += 64) s = fmaf(row[k], v[k], s);
#pragma unroll
  for (int off = 32; off; off >>= 1) s += __shfl_xor(s, off, 64);
  if (lane == 0) out[w] = s;
}

// ---------------- CSR build ----------------
__global__ void deg_count_k(const int* __restrict__ edst, int E, int N, int* __restrict__ deg) {
  int i = blockIdx.x * 256 + threadIdx.x;
  if (i >= E + N) return;
  int d = (i < E) ? edst[i] : (i - E);
  atomicAdd(&deg[d], 1);
}

__global__ __launch_bounds__(1024) void scan1_k(const int* __restrict__ deg, int n,
                                                int* __restrict__ ex, int* __restrict__ bsum) {
  __shared__ int sm[1024];
  int t = threadIdx.x;
  int idx = blockIdx.x * 1024 + t;
  int v = (idx < n) ? deg[idx] : 0;
  sm[t] = v;
  __syncthreads();
  for (int off = 1; off < 1024; off <<= 1) {
    int tv = (t >= off) ? sm[t - off] : 0;
    __syncthreads();
    sm[t] += tv;
    __syncthreads();
  }
  if (idx < n) ex[idx] = sm[t] - v;
  if (t == 1023) bsum[blockIdx.x] = sm[t];
}

__global__ void scan2_k(int* __restrict__ bsum, int nb) {
  if (threadIdx.x == 0 && blockIdx.x == 0) {
    int run = 0;
    for (int b = 0; b < nb; ++b) { int x = bsum[b]; bsum[b] = run; run += x; }
  }
}

__global__ void scan3_k(int* __restrict__ ex, const int* __restrict__ bsum, int n, int total,
                        int* __restrict__ cursor) {
  int idx = blockIdx.x * 256 + threadIdx.x;
  if (idx < n) {
    int v = ex[idx] + bsum[idx >> 10];
    ex[idx] = v;
    cursor[idx] = v;
  }
  if (idx == 0) ex[n] = total;
}

// range-filtered scatter: only edges with dst in [d0,d1); write region fits L2, merges.
__global__ void scatter_range_k(const int* __restrict__ esrc, const int* __restrict__ edst,
                                int E, int N, int d0, int d1,
                                int* __restrict__ cursor, int* __restrict__ csr_src) {
  int i = blockIdx.x * 256 + threadIdx.x;
  if (i >= E + N) return;
  int d = (i < E) ? edst[i] : (i - E);
  if (d < d0 || d >= d1) return;
  int s = (i < E) ? esrc[i] : d;
  int pos = atomicAdd(&cursor[d], 1);
  csr_src[pos] = s;
}

// ---------------- GAT aggregation: wave/dst; quarter-wave uint4 gather, UNIFORM exec ----------------
// Output: pre-split f16 h/l pair (next GEMM's A). Optional fused dot: ad_out[w] = out_row . wvd.
__global__ __launch_bounds__(256) void gat_agg_k(const unsigned short* __restrict__ hbf,
                                                 const float* __restrict__ a_src,
                                                 const float* __restrict__ a_dst, const int* __restrict__ rowstart,
                                                 const int* __restrict__ csr_src, const float* __restrict__ bias,
                                                 _Float16* __restrict__ oh, _Float16* __restrict__ ol,
                                                 const float* __restrict__ wvd, float* __restrict__ ad_out,
                                                 int N) {
  int w = (blockIdx.x * blockDim.x + threadIdx.x) >> 6;
  int lane = threadIdx.x & 63;
  if (w >= N) return;
  int s0 = rowstart[w];
  int s1 = rowstart[w + 1];
  int deg = s1 - s0;
  float ad = a_dst[w];

  int sA = 0;
  float eA = -3.0e38f;
  if (lane < deg) {
    sA = csr_src[s0 + lane];
    eA = lrelu(a_src[sA] + ad);
  }
  float m = eA;
  for (int j = s0 + 64 + lane; j < s1; j += 64) {
    int s = csr_src[j];
    m = fmaxf(m, lrelu(a_src[s] + ad));
  }
#pragma unroll
  for (int off = 32; off; off >>= 1) m = fmaxf(m, __shfl_xor(m, off, 64));

  float preg = (lane < deg) ? __expf(eA - m) : 0.f;
  float den = preg;
  for (int j = s0 + 64 + lane; j < s1; j += 64) {
    int s = csr_src[j];
    den += __expf(lrelu(a_src[s] + ad) - m);
  }
#pragma unroll
  for (int off = 32; off; off >>= 1) den += __shfl_xor(den, off, 64);
  float inv = 1.f / den;

  // quarter-wave uint4 gather; loop bound padded to multiple of 4 so exec is FULL at
  // every __shfl (divergent-exec shfl corrupted rounds 2/9). Padded edges: preg=0.
  const int q  = lane >> 4;
  const int sl = lane & 15;
  const uint4* hrow4 = (const uint4*)hbf;
  float acc[8];
#pragma unroll
  for (int i = 0; i < 8; ++i) acc[i] = 0.f;

  int lim  = deg < 64 ? deg : 64;
  int lim4 = (lim + 3) & ~3;
  for (int jj = 0; jj < lim4; jj += 4) {
    int e = jj + q;
    int s = __shfl(sA, e, 64);
    float wgt = __shfl(preg, e, 64) * inv;
    uint4 u = hrow4[(size_t)s * 16 + sl];
    acc[0] = fmaf(wgt, bflo(u.x), acc[0]);
    acc[1] = fmaf(wgt, bfhi(u.x), acc[1]);
    acc[2] = fmaf(wgt, bflo(u.y), acc[2]);
    acc[3] = fmaf(wgt, bfhi(u.y), acc[3]);
    acc[4] = fmaf(wgt, bflo(u.z), acc[4]);
    acc[5] = fmaf(wgt, bfhi(u.z), acc[5]);
    acc[6] = fmaf(wgt, bflo(u.w), acc[6]);
    acc[7] = fmaf(wgt, bfhi(u.w), acc[7]);
  }
  for (int j = s0 + 64 + q; j < s1; j += 4) {  // rare deg>64 tail: shfl-free
    int s = csr_src[j];
    float wgt = __expf(lrelu(a_src[s] + ad) - m) * inv;
    uint4 u = hrow4[(size_t)s * 16 + sl];
    acc[0] = fmaf(wgt, bflo(u.x), acc[0]);
    acc[1] = fmaf(wgt, bfhi(u.x), acc[1]);
    acc[2] = fmaf(wgt, bflo(u.y), acc[2]);
    acc[3] = fmaf(wgt, bfhi(u.y), acc[3]);
    acc[4] = fmaf(wgt, bflo(u.z), acc[4]);
    acc[5] = fmaf(wgt, bfhi(u.z), acc[5]);
    acc[6] = fmaf(wgt, bflo(u.w), acc[6]);
    acc[7] = fmaf(wgt, bfhi(u.w), acc[7]);
  }
#pragma unroll
  for (int i = 0; i < 8; ++i) {
    acc[i] += __shfl_xor(acc[i], 16, 64);
    acc[i] += __shfl_xor(acc[i], 32, 64);
  }
  if (q == 0) {   // lanes 0..15 all active; intra-quarter shfl reads active lanes only (r7-validated)
    float4 b0 = *(const float4*)&bias[8 * sl];
    float4 b1 = *(const float4*)&bias[8 * sl + 4];
    float v[8];
    v[0] = fmaxf(acc[0] + b0.x, 0.f);
    v[1] = fmaxf(acc[1] + b0.y, 0.f);
    v[2] = fmaxf(acc[2] + b0.z, 0.f);
    v[3] = fmaxf(acc[3] + b0.w, 0.f);
    v[4] = fmaxf(acc[4] + b1.x, 0.f);
    v[5] = fmaxf(acc[5] + b1.y, 0.f);
    v[6] = fmaxf(acc[6] + b1.z, 0.f);
    v[7] = fmaxf(acc[7] + b1.w, 0.f);
    half8 vh, vl;
#pragma unroll
    for (int i = 0; i < 8; ++i) {
      h2 s = split2h(v[i]);
      vh[i] = s.h;
      vl[i] = s.l;
    }
    size_t base = (size_t)w * 128 + 8 * sl;
    *(half8*)&oh[base] = vh;
    *(half8*)&ol[base] = vl;
    if (wvd) {
      float4 w0 = *(const float4*)&wvd[8 * sl];
      float4 w1 = *(const float4*)&wvd[8 * sl + 4];
      float dd = v[0] * w0.x + v[1] * w0.y + v[2] * w0.z + v[3] * w0.w
               + v[4] * w1.x + v[5] * w1.y + v[6] * w1.z + v[7] * w1.w;
      dd += __shfl_xor(dd, 1, 64);
      dd += __shfl_xor(dd, 2, 64);
      dd += __shfl_xor(dd, 4, 64);
      dd += __shfl_xor(dd, 8, 64);
      if (sl == 0) ad_out[w] = dd;
    }
  }
}

// ---------------- BatchNorm stats / finalize ----------------
__global__ __launch_bounds__(256) void bn_stats_k(const float* __restrict__ z, int N,
                                                  float* __restrict__ sums, float* __restrict__ sumsq) {
  __shared__ float ls[256], lq[256];
  int col = threadIdx.x & 63;
  int rg = threadIdx.x >> 6;
  float s = 0.f, q = 0.f;
  for (int r = blockIdx.x * 4 + rg; r < N; r += gridDim.x * 4) {
    float v = z[(size_t)r * 64 + col];
    s += v;
    q = fmaf(v, v, q);
  }
  ls[threadIdx.x] = s;
  lq[threadIdx.x] = q;
  __syncthreads();
  if (threadIdx.x < 64) {
    s = ls[col] + ls[col + 64] + ls[col + 128] + ls[col + 192];
    q = lq[col] + lq[col + 64] + lq[col + 128] + lq[col + 192];
    atomicAdd(&sums[col], s);
    atomicAdd(&sumsq[col], q);
  }
}

__global__ void bn_finalize_k(const float* __restrict__ sums, const float* __restrict__ sumsq,
                              const float* __restrict__ gamma, const float* __restrict__ beta,
                              int N, float* __restrict__ scale, float* __restrict__ shift) {
  int c = threadIdx.x;
  if (c >= 64) return;
  float mean = sums[c] / (float)N;
  float var = sumsq[c] / (float)N - mean * mean;
  float rs = rsqrtf(var + BN_EPS);
  float sc = gamma[c] * rs;
  scale[c] = sc;
  shift[c] = beta[c] - mean * sc;
}

// ---------------- fused BN-apply + ReLU + FC2 + log_softmax (thread per node) ----------------
__global__ __launch_bounds__(256) void fc2_lsm_k(const float* __restrict__ z, const float* __restrict__ scale,
                                                 const float* __restrict__ shift, const float* __restrict__ w,
                                                 const float* __restrict__ b, float* __restrict__ out, int N) {
  int n = blockIdx.x * 256 + threadIdx.x;
  if (n >= N) return;
  float o[40];
#pragma unroll
  for (int c = 0; c < 40; ++c) o[c] = b[c];
  const float* zr = z + (size_t)n * 64;
  for (int k = 0; k < 64; ++k) {
    float v = fmaxf(fmaf(zr[k], scale[k], shift[k]), 0.f);
#pragma unroll
    for (int c = 0; c < 40; ++c) o[c] = fmaf(v, w[k * 40 + c], o[c]);
  }
  float mx = o[0];
#pragma unroll
  for (int c = 1; c < 40; ++c) mx = fmaxf(mx, o[c]);
  float s = 0.f;
#pragma unroll
  for (int c = 0; c < 40; ++c) s += __expf(o[c] - mx);
  float ls = __logf(s);
  float* orow = out + (size_t)n * 40;
#pragma unroll
  for (int c = 0; c < 40; ++c) orow[c] = o[c] - mx - ls;
}

// ---------------- launch ----------------
static inline char* al16(char* p) { return (char*)(((size_t)p + 15) & ~(size_t)15); }

extern "C" void kernel_launch(void* const* d_in, const int* in_sizes, int n_in,
                              void* d_out, int out_size, void* d_ws, size_t ws_size,
                              hipStream_t stream) {
  const float* x     = (const float*)d_in[0];
  const int*   eidx  = (const int*)d_in[1];
  const float* W1s   = (const float*)d_in[2];
  const float* W1d   = (const float*)d_in[3];
  const float* att1s = (const float*)d_in[4];
  const float* att1d = (const float*)d_in[5];
  const float* b1    = (const float*)d_in[6];
  const float* W2s   = (const float*)d_in[7];
  const float* W2d   = (const float*)d_in[8];
  const float* att2s = (const float*)d_in[9];
  const float* att2d = (const float*)d_in[10];
  const float* b2    = (const float*)d_in[11];
  const float* fc1w  = (const float*)d_in[12];
  const float* fc1b  = (const float*)d_in[13];
  const float* gamma = (const float*)d_in[14];
  const float* beta  = (const float*)d_in[15];
  const float* fc2w  = (const float*)d_in[16];
  const float* fc2b  = (const float*)d_in[17];
  float* out = (float*)d_out;

  const int N  = in_sizes[0] / 256;
  const int E  = in_sizes[1] / 2;
  const int ET = E + N;
  const int DIN = 256, H1 = 128;

  // workspace layout (~105 MB)
  char* p = (char*)d_ws;
  unsigned short* bhA = (unsigned short*)p; p += (size_t)N * 128 * 2;  // bf16 gather source
  _Float16* hAh = (_Float16*)p;  p += (size_t)N * 128 * 2;             // agg out, f16 hi (next A)
  _Float16* hAl = (_Float16*)p;  p += (size_t)N * 128 * 2;             // agg out, f16 lo
  float* hF = (float*)p;         p += (size_t)N * 64 * 4;              // FC1 fp32 out
  int* deg      = (int*)p;     p += (size_t)N * 4;
  int* rowstart = (int*)p;     p += (size_t)(N + 1) * 4;
  int* cursor   = (int*)p;     p += (size_t)N * 4;
  int* csr_src  = (int*)p;     p += (size_t)ET * 4;
  float* a_src  = (float*)p;   p += (size_t)N * 4;
  float* a_dst  = (float*)p;   p += (size_t)N * 4;
  float* a_dst2 = (float*)p;   p += (size_t)N * 4;
  float* wvd1   = (float*)p;   p += 256 * 4;
  float* wvd2   = (float*)p;   p += 128 * 4;
  float* sums   = (float*)p;   p += 64 * 4;
  float* sumsq  = (float*)p;   p += 64 * 4;
  float* scale  = (float*)p;   p += 64 * 4;
  float* shift  = (float*)p;   p += 64 * 4;
  int* bsum     = (int*)p;     p += 256 * 4;
  p = al16(p);
  _Float16* B1h = (_Float16*)p; p += (size_t)256 * 128 * 2;
  _Float16* B1l = (_Float16*)p; p += (size_t)256 * 128 * 2;
  _Float16* B2h = (_Float16*)p; p += (size_t)128 * 128 * 2;
  _Float16* B2l = (_Float16*)p; p += (size_t)128 * 128 * 2;
  _Float16* Bfh = (_Float16*)p; p += (size_t)128 * 64 * 2;
  _Float16* Bfl = (_Float16*)p; p += (size_t)128 * 64 * 2;

  const int* esrc = eidx;
  const int* edst = eidx + E;

  // ---- CSR build (by dst, self-loops appended) ----
  hipMemsetAsync(deg, 0, (size_t)N * 4, stream);
  deg_count_k<<<(ET + 255) / 256, 256, 0, stream>>>(edst, E, N, deg);
  int nb = (N + 1023) / 1024;
  scan1_k<<<nb, 1024, 0, stream>>>(deg, N, rowstart, bsum);
  scan2_k<<<1, 64, 0, stream>>>(bsum, nb);
  scan3_k<<<(N + 255) / 256, 256, 0, stream>>>(rowstart, bsum, N, ET, cursor);
  {
    const int NR = 8;
    int step = (N + NR - 1) / NR;
    for (int r = 0; r < NR; ++r) {
      int d0 = r * step;
      int d1 = d0 + step < N ? d0 + step : N;
      scatter_range_k<<<(ET + 255) / 256, 256, 0, stream>>>(esrc, edst, E, N, d0, d1, cursor, csr_src);
    }
  }

  // ---- one-time B frag pre-splits + a_dst fold vectors ----
  bfrag_k<<<16, 256, 0, stream>>>(W1s, B1h, B1l, 256, 128);
  bfrag_k<<<8, 256, 0, stream>>>(W2s, B2h, B2l, 128, 128);
  bfrag_k<<<4, 256, 0, stream>>>(fc1w, Bfh, Bfl, 128, 64);
  matvec_k<<<64, 256, 0, stream>>>(W1d, att1d, wvd1, 256, 128);   // wvd1 = W1_dst @ att1_dst
  matvec_k<<<32, 256, 0, stream>>>(W2d, att2d, wvd2, 128, 128);

  const int gemm_blocks = (N + 127) / 128;

  // ---- GAT layer 1 ----
  gemm3h_k<128><<<gemm_blocks, 256, 0, stream>>>(x, B1h, B1l, (float*)nullptr, bhA, att1s, a_src,
                                                 N, DIN, (const float*)nullptr);
  matvec_k<<<(N + 3) / 4, 256, 0, stream>>>(x, wvd1, a_dst, N, DIN);
  gat_agg_k<<<(N + 3) / 4, 256, 0, stream>>>(bhA, a_src, a_dst, rowstart, csr_src, b1,
                                             hAh, hAl, wvd2, a_dst2, N);

  // ---- GAT layer 2 (A pre-split; a_dst2 already fused above) ----
  gemm3p_k<128><<<gemm_blocks, 256, 0, stream>>>(hAh, hAl, B2h, B2l, (float*)nullptr, bhA, att2s, a_src,
                                                 N, H1, (const float*)nullptr);
  gat_agg_k<<<(N + 3) / 4, 256, 0, stream>>>(bhA, a_src, a_dst2, rowstart, csr_src, b2,
                                             hAh, hAl, (const float*)nullptr, (float*)nullptr, N);

  // ---- FC1 (+bias) -> BN -> fused BN-apply+ReLU+FC2+log_softmax ----
  gemm3p_k<64><<<gemm_blocks, 256, 0, stream>>>(hAh, hAl, Bfh, Bfl, hF, (unsigned short*)nullptr,
                                                (const float*)nullptr, (float*)nullptr, N, H1, fc1b);
  hipMemsetAsync(sums, 0, 128 * sizeof(float), stream);
  bn_stats_k<<<512, 256, 0, stream>>>(hF, N, sums, sumsq);
  bn_finalize_k<<<1, 64, 0, stream>>>(sums, sumsq, gamma, beta, N, scale, shift);
  fc2_lsm_k<<<(N + 255) / 256, 256, 0, stream>>>(hF, scale, shift, fc2w, fc2b, out, N);
}

// Round 12
// 717.121 us; speedup vs baseline: 1.4608x; 1.0653x over previous
//
#include <hip/hip_runtime.h>
#include <cstddef>

#define LSLOPE 0.2f
#define BN_EPS 1e-5f

__device__ __forceinline__ float lrelu(float x) { return x > 0.f ? x : LSLOPE * x; }

using half4 = __attribute__((ext_vector_type(4))) _Float16;
using half8 = __attribute__((ext_vector_type(8))) _Float16;
using f32x4 = __attribute__((ext_vector_type(4))) float;

struct h2 { _Float16 h, l; };
__device__ __forceinline__ h2 split2h(float x) {
  h2 r;
  r.h = (_Float16)x;
  r.l = (_Float16)(x - (float)r.h);
  return r;
}

__device__ __forceinline__ unsigned short f2bf(float x) {
  unsigned u = __float_as_uint(x);
  unsigned r = (u + 0x7fffu + ((u >> 16) & 1u)) >> 16;
  return (unsigned short)r;
}
__device__ __forceinline__ float bflo(unsigned int u) { return __uint_as_float(u << 16); }
__device__ __forceinline__ float bfhi(unsigned int u) { return __uint_as_float(u & 0xffff0000u); }

// ---------- prep bodies ----------
__device__ __forceinline__ void bfrag_body(const float* __restrict__ B, _Float16* __restrict__ bh,
                                           _Float16* __restrict__ bl, int K, int M, int t) {
  int KB = K >> 5;
  int lane = t & 63;
  int ckb  = t >> 6;
  int c  = ckb / KB, kb = ckb % KB;
  int mr = lane & 15, quad = lane >> 4;
  int col = c * 16 + mr;
  size_t obase = (size_t)t * 8;
#pragma unroll
  for (int j = 0; j < 8; ++j) {
    int k = kb * 32 + quad * 8 + j;
    h2 s = split2h(B[(size_t)k * M + col]);
    bh[obase + j] = s.h;
    bl[obase + j] = s.l;
  }
}

__device__ __forceinline__ void matvec_body(const float* __restrict__ A, const float* __restrict__ v,
                                            float* __restrict__ out, int R, int K, int t) {
  int w = t >> 6;
  int lane = t & 63;
  if (w >= R) return;
  const float* row = A + (size_t)w * K;
  float s = 0.f;
  for (int k = lane; k < K; k += 64) s = fmaf(row[k], v[k], s);
#pragma unroll
  for (int off = 32; off; off >>= 1) s += __shfl_xor(s, off, 64);
  if (lane == 0) out[w] = s;
}

// one kernel: 3 B-frag splits + 2 weight matvecs (block-range dispatch)
__global__ __launch_bounds__(256) void prep_k(const float* __restrict__ W1s, const float* __restrict__ W2s,
                                              const float* __restrict__ fc1w,
                                              const float* __restrict__ W1d, const float* __restrict__ att1d,
                                              const float* __restrict__ W2d, const float* __restrict__ att2d,
                                              _Float16* B1h, _Float16* B1l, _Float16* B2h, _Float16* B2l,
                                              _Float16* Bfh, _Float16* Bfl,
                                              float* wvd1, float* wvd2) {
  int b = blockIdx.x;
  int tid = threadIdx.x;
  if (b < 16)       bfrag_body(W1s, B1h, B1l, 256, 128, b * 256 + tid);
  else if (b < 24)  bfrag_body(W2s, B2h, B2l, 128, 128, (b - 16) * 256 + tid);
  else if (b < 28)  bfrag_body(fc1w, Bfh, Bfl, 128, 64, (b - 24) * 256 + tid);
  else if (b < 92)  matvec_body(W1d, att1d, wvd1, 256, 128, (b - 28) * 256 + tid);
  else              matvec_body(W2d, att2d, wvd2, 128, 128, (b - 92) * 256 + tid);
}

// ---------- f16 3-term MFMA GEMM, fp32 A, dbuf LDS; fused asrc (C.attv) + adout (A.wvd) ----------
template<int MCOLS>
__global__ __launch_bounds__(256) void gemm3h_k(const float* __restrict__ A,
                                                const _Float16* __restrict__ Bh,
                                                const _Float16* __restrict__ Bl,
                                                float* __restrict__ Cf,
                                                unsigned short* __restrict__ Cbf,
                                                const float* __restrict__ attv,
                                                float* __restrict__ asrc,
                                                const float* __restrict__ wvd,
                                                float* __restrict__ adout,
                                                int N, int K,
                                                const float* __restrict__ bias) {
  constexpr int CT = MCOLS / 16;
  __shared__ __align__(16) _Float16 sAh[2][128 * 32];
  __shared__ __align__(16) _Float16 sAl[2][128 * 32];
  const int tid  = threadIdx.x;
  const int row0 = blockIdx.x * 128;
  const int wv   = tid >> 6;
  const int lane = tid & 63;
  const int quad = lane >> 4;
  const int mr   = lane & 15;
  const int KB   = K >> 5;

  int srow[4], skc[4], soff[4];
  bool sok[4];
#pragma unroll
  for (int cc = 0; cc < 4; ++cc) {
    int s = tid + cc * 256;
    srow[cc] = s >> 3;
    skc[cc]  = (s & 7) << 2;
    soff[cc] = srow[cc] * 32 + ((skc[cc] + srow[cc] * 8) & 31);
    sok[cc]  = (row0 + srow[cc]) < N;
  }

  f32x4 acc[2][CT];
#pragma unroll
  for (int r = 0; r < 2; ++r)
#pragma unroll
    for (int c = 0; c < CT; ++c) acc[r][c] = (f32x4){0.f, 0.f, 0.f, 0.f};
  float pad[2] = {0.f, 0.f};

  float4 pf[4];
#pragma unroll
  for (int cc = 0; cc < 4; ++cc)
    pf[cc] = sok[cc] ? *(const float4*)&A[(size_t)(row0 + srow[cc]) * K + skc[cc]]
                     : make_float4(0.f, 0.f, 0.f, 0.f);
#pragma unroll
  for (int cc = 0; cc < 4; ++cc) {
    h2 s0 = split2h(pf[cc].x), s1 = split2h(pf[cc].y), s2 = split2h(pf[cc].z), s3 = split2h(pf[cc].w);
    half4 h4, l4;
    h4[0] = s0.h; h4[1] = s1.h; h4[2] = s2.h; h4[3] = s3.h;
    l4[0] = s0.l; l4[1] = s1.l; l4[2] = s2.l; l4[3] = s3.l;
    *(half4*)&sAh[0][soff[cc]] = h4;
    *(half4*)&sAl[0][soff[cc]] = l4;
  }
  __syncthreads();

  for (int kb = 0; kb < KB; ++kb) {
    const int cur = kb & 1, nxt = cur ^ 1;
    const int kk = kb << 5;
    if (kb + 1 < KB) {
      const int kn = (kb + 1) << 5;
#pragma unroll
      for (int cc = 0; cc < 4; ++cc)
        pf[cc] = sok[cc] ? *(const float4*)&A[(size_t)(row0 + srow[cc]) * K + kn + skc[cc]]
                         : make_float4(0.f, 0.f, 0.f, 0.f);
    }

    half8 ah[2], al[2];
#pragma unroll
    for (int r = 0; r < 2; ++r) {
      int row = wv * 32 + r * 16 + mr;
      int off = row * 32 + ((quad + row) & 3) * 8;
      ah[r] = *(const half8*)&sAh[cur][off];
      al[r] = *(const half8*)&sAl[cur][off];
    }
    if (wvd) {   // fused a_dst partial: A-row (hi+lo) . wvd over this K-tile
      const float* wp = wvd + kk + quad * 8;
#pragma unroll
      for (int r = 0; r < 2; ++r) {
        float d = 0.f;
#pragma unroll
        for (int j = 0; j < 8; ++j) {
          float av = wp[j];
          d = fmaf((float)ah[r][j], av, d);
          d = fmaf((float)al[r][j], av, d);
        }
        pad[r] += d;
      }
    }
    const _Float16* bb_h = Bh + ((size_t)kb * 64 + lane) * 8;
    const _Float16* bb_l = Bl + ((size_t)kb * 64 + lane) * 8;
    const size_t cstride = (size_t)KB * 512;
#pragma unroll
    for (int c0 = 0; c0 < CT; c0 += 4) {
      half8 bh4[4], bl4[4];
#pragma unroll
      for (int c = 0; c < 4; ++c) {
        size_t o = (size_t)(c0 + c) * cstride;
        bh4[c] = *(const half8*)&bb_h[o];
        bl4[c] = *(const half8*)&bb_l[o];
      }
#pragma unroll
      for (int r = 0; r < 2; ++r)
#pragma unroll
        for (int c = 0; c < 4; ++c) {
          f32x4 a = acc[r][c0 + c];
          a = __builtin_amdgcn_mfma_f32_16x16x32_f16(al[r], bh4[c], a, 0, 0, 0);
          a = __builtin_amdgcn_mfma_f32_16x16x32_f16(ah[r], bl4[c], a, 0, 0, 0);
          a = __builtin_amdgcn_mfma_f32_16x16x32_f16(ah[r], bh4[c], a, 0, 0, 0);
          acc[r][c0 + c] = a;
        }
    }
    if (kb + 1 < KB) {
#pragma unroll
      for (int cc = 0; cc < 4; ++cc) {
        h2 s0 = split2h(pf[cc].x), s1 = split2h(pf[cc].y), s2 = split2h(pf[cc].z), s3 = split2h(pf[cc].w);
        half4 h4, l4;
        h4[0] = s0.h; h4[1] = s1.h; h4[2] = s2.h; h4[3] = s3.h;
        l4[0] = s0.l; l4[1] = s1.l; l4[2] = s2.l; l4[3] = s3.l;
        *(half4*)&sAh[nxt][soff[cc]] = h4;
        *(half4*)&sAl[nxt][soff[cc]] = l4;
      }
    }
    __syncthreads();
  }

  // epilogue: D col = lane&15, row = (lane>>4)*4 + reg  [m89/m91-verified]
  float pa[2][4];
#pragma unroll
  for (int r = 0; r < 2; ++r)
#pragma unroll
    for (int q = 0; q < 4; ++q) pa[r][q] = 0.f;

#pragma unroll
  for (int r = 0; r < 2; ++r)
#pragma unroll
    for (int c = 0; c < CT; ++c) {
      float av = attv ? attv[c * 16 + mr] : 0.f;
#pragma unroll
      for (int q = 0; q < 4; ++q) {
        int grow = row0 + wv * 32 + r * 16 + quad * 4 + q;
        float val = acc[r][c][q];
        if (bias) val += bias[c * 16 + mr];
        if (grow < N) {
          int gcol = c * 16 + mr;
          if (Cf)  Cf[(size_t)grow * MCOLS + gcol] = val;
          if (Cbf) Cbf[(size_t)grow * 128 + gcol] = f2bf(val);
        }
        if (attv) pa[r][q] = fmaf(val, av, pa[r][q]);
      }
    }
  if (attv) {
#pragma unroll
    for (int r = 0; r < 2; ++r)
#pragma unroll
      for (int q = 0; q < 4; ++q) {
        float p2 = pa[r][q];
        p2 += __shfl_xor(p2, 1, 64);
        p2 += __shfl_xor(p2, 2, 64);
        p2 += __shfl_xor(p2, 4, 64);
        p2 += __shfl_xor(p2, 8, 64);
        int grow = row0 + wv * 32 + r * 16 + quad * 4 + q;
        if (mr == 0 && grow < N) asrc[grow] = p2;
      }
  }
  if (wvd) {   // reduce a_dst partials over quads (full exec)
#pragma unroll
    for (int r = 0; r < 2; ++r) {
      float d = pad[r];
      d += __shfl_xor(d, 16, 64);
      d += __shfl_xor(d, 32, 64);
      int grow = row0 + wv * 32 + r * 16 + mr;
      if (quad == 0 && grow < N) adout[grow] = d;
    }
  }
}

// ---------- f16 3-term MFMA GEMM, PRE-SPLIT f16 A (h/l pair), double-buffered ----------
template<int MCOLS>
__global__ __launch_bounds__(256) void gemm3p_k(const _Float16* __restrict__ Ah,
                                                const _Float16* __restrict__ Al,
                                                const _Float16* __restrict__ Bh,
                                                const _Float16* __restrict__ Bl,
                                                float* __restrict__ Cf,
                                                unsigned short* __restrict__ Cbf,
                                                const float* __restrict__ attv,
                                                float* __restrict__ asrc,
                                                int N, int K,
                                                const float* __restrict__ bias) {
  constexpr int CT = MCOLS / 16;
  __shared__ __align__(16) _Float16 sAh[2][128 * 32];
  __shared__ __align__(16) _Float16 sAl[2][128 * 32];
  const int tid  = threadIdx.x;
  const int row0 = blockIdx.x * 128;
  const int wv   = tid >> 6;
  const int lane = tid & 63;
  const int quad = lane >> 4;
  const int mr   = lane & 15;
  const int KB   = K >> 5;

  int srow[2], sk8[2], soff[2];
  bool sok[2];
#pragma unroll
  for (int cc = 0; cc < 2; ++cc) {
    int s = tid + cc * 256;
    srow[cc] = s >> 2;
    sk8[cc]  = (s & 3) << 3;
    soff[cc] = srow[cc] * 32 + ((sk8[cc] + srow[cc] * 8) & 31);
    sok[cc]  = (row0 + srow[cc]) < N;
  }

  f32x4 acc[2][CT];
#pragma unroll
  for (int r = 0; r < 2; ++r)
#pragma unroll
    for (int c = 0; c < CT; ++c) acc[r][c] = (f32x4){0.f, 0.f, 0.f, 0.f};

  uint4 ph[2], pl[2];
  const uint4 z4 = make_uint4(0u, 0u, 0u, 0u);
#pragma unroll
  for (int cc = 0; cc < 2; ++cc) {
    size_t go = (size_t)(row0 + srow[cc]) * K + sk8[cc];
    ph[cc] = sok[cc] ? *(const uint4*)&Ah[go] : z4;
    pl[cc] = sok[cc] ? *(const uint4*)&Al[go] : z4;
  }
#pragma unroll
  for (int cc = 0; cc < 2; ++cc) {
    *(uint4*)&sAh[0][soff[cc]] = ph[cc];
    *(uint4*)&sAl[0][soff[cc]] = pl[cc];
  }
  __syncthreads();

  for (int kb = 0; kb < KB; ++kb) {
    const int cur = kb & 1, nxt = cur ^ 1;
    if (kb + 1 < KB) {
      const int kk = (kb + 1) << 5;
#pragma unroll
      for (int cc = 0; cc < 2; ++cc) {
        size_t go = (size_t)(row0 + srow[cc]) * K + kk + sk8[cc];
        ph[cc] = sok[cc] ? *(const uint4*)&Ah[go] : z4;
        pl[cc] = sok[cc] ? *(const uint4*)&Al[go] : z4;
      }
    }

    half8 ah[2], al[2];
#pragma unroll
    for (int r = 0; r < 2; ++r) {
      int row = wv * 32 + r * 16 + mr;
      int off = row * 32 + ((quad + row) & 3) * 8;
      ah[r] = *(const half8*)&sAh[cur][off];
      al[r] = *(const half8*)&sAl[cur][off];
    }
    const _Float16* bb_h = Bh + ((size_t)kb * 64 + lane) * 8;
    const _Float16* bb_l = Bl + ((size_t)kb * 64 + lane) * 8;
    const size_t cstride = (size_t)KB * 512;
#pragma unroll
    for (int c0 = 0; c0 < CT; c0 += 4) {
      half8 bh4[4], bl4[4];
#pragma unroll
      for (int c = 0; c < 4; ++c) {
        size_t o = (size_t)(c0 + c) * cstride;
        bh4[c] = *(const half8*)&bb_h[o];
        bl4[c] = *(const half8*)&bb_l[o];
      }
#pragma unroll
      for (int r = 0; r < 2; ++r)
#pragma unroll
        for (int c = 0; c < 4; ++c) {
          f32x4 a = acc[r][c0 + c];
          a = __builtin_amdgcn_mfma_f32_16x16x32_f16(al[r], bh4[c], a, 0, 0, 0);
          a = __builtin_amdgcn_mfma_f32_16x16x32_f16(ah[r], bl4[c], a, 0, 0, 0);
          a = __builtin_amdgcn_mfma_f32_16x16x32_f16(ah[r], bh4[c], a, 0, 0, 0);
          acc[r][c0 + c] = a;
        }
    }
    if (kb + 1 < KB) {
#pragma unroll
      for (int cc = 0; cc < 2; ++cc) {
        *(uint4*)&sAh[nxt][soff[cc]] = ph[cc];
        *(uint4*)&sAl[nxt][soff[cc]] = pl[cc];
      }
    }
    __syncthreads();
  }

  float pa[2][4];
#pragma unroll
  for (int r = 0; r < 2; ++r)
#pragma unroll
    for (int q = 0; q < 4; ++q) pa[r][q] = 0.f;

#pragma unroll
  for (int r = 0; r < 2; ++r)
#pragma unroll
    for (int c = 0; c < CT; ++c) {
      float av = attv ? attv[c * 16 + mr] : 0.f;
#pragma unroll
      for (int q = 0; q < 4; ++q) {
        int grow = row0 + wv * 32 + r * 16 + quad * 4 + q;
        float val = acc[r][c][q];
        if (bias) val += bias[c * 16 + mr];
        if (grow < N) {
          int gcol = c * 16 + mr;
          if (Cf)  Cf[(size_t)grow * MCOLS + gcol] = val;
          if (Cbf) Cbf[(size_t)grow * 128 + gcol] = f2bf(val);
        }
        if (attv) pa[r][q] = fmaf(val, av, pa[r][q]);
      }
    }
  if (attv) {
#pragma unroll
    for (int r = 0; r < 2; ++r)
#pragma unroll
      for (int q = 0; q < 4; ++q) {
        float p2 = pa[r][q];
        p2 += __shfl_xor(p2, 1, 64);
        p2 += __shfl_xor(p2, 2, 64);
        p2 += __shfl_xor(p2, 4, 64);
        p2 += __shfl_xor(p2, 8, 64);
        int grow = row0 + wv * 32 + r * 16 + quad * 4 + q;
        if (mr == 0 && grow < N) asrc[grow] = p2;
      }
  }
}

// ---------------- CSR build ----------------
__global__ void deg_count_k(const int* __restrict__ edst, int E, int N, int* __restrict__ deg) {
  int i = blockIdx.x * 256 + threadIdx.x;
  if (i >= E + N) return;
  int d = (i < E) ? edst[i] : (i - E);
  atomicAdd(&deg[d], 1);
}

__global__ __launch_bounds__(1024) void scan1_k(const int* __restrict__ deg, int n,
                                                int* __restrict__ ex, int* __restrict__ bsum) {
  __shared__ int sm[1024];
  int t = threadIdx.x;
  int idx = blockIdx.x * 1024 + t;
  int v = (idx < n) ? deg[idx] : 0;
  sm[t] = v;
  __syncthreads();
  for (int off = 1; off < 1024; off <<= 1) {
    int tv = (t >= off) ? sm[t - off] : 0;
    __syncthreads();
    sm[t] += tv;
    __syncthreads();
  }
  if (idx < n) ex[idx] = sm[t] - v;
  if (t == 1023) bsum[blockIdx.x] = sm[t];
}

// scan3 with inlined block-sum prefix (scan2 eliminated): bsum holds RAW per-block sums.
__global__ void scan3_k(int* __restrict__ ex, const int* __restrict__ bsum, int n, int nb, int total,
                        int* __restrict__ cursor) {
  __shared__ int pbase[2];
  int idx = blockIdx.x * 256 + threadIdx.x;
  int bin0 = (blockIdx.x * 256) >> 10;
  if (threadIdx.x < 2) {
    int b = bin0 + threadIdx.x;
    int s = 0;
    for (int i = 0; i < b && i < nb; ++i) s += bsum[i];
    pbase[threadIdx.x] = s;
  }
  __syncthreads();
  if (idx < n) {
    int v = ex[idx] + pbase[(idx >> 10) - bin0];
    ex[idx] = v;
    cursor[idx] = v;
  }
  if (idx == 0) ex[n] = total;
}

// range-filtered scatter: only edges with dst in [d0,d1); write region fits L2, merges.
__global__ void scatter_range_k(const int* __restrict__ esrc, const int* __restrict__ edst,
                                int E, int N, int d0, int d1,
                                int* __restrict__ cursor, int* __restrict__ csr_src) {
  int i = blockIdx.x * 256 + threadIdx.x;
  if (i >= E + N) return;
  int d = (i < E) ? edst[i] : (i - E);
  if (d < d0 || d >= d1) return;
  int s = (i < E) ? esrc[i] : d;
  int pos = atomicAdd(&cursor[d], 1);
  csr_src[pos] = s;
}

// ---------------- GAT aggregation: wave/dst; quarter-wave uint4 gather, UNIFORM exec ----------------
__global__ __launch_bounds__(256) void gat_agg_k(const unsigned short* __restrict__ hbf,
                                                 const float* __restrict__ a_src,
                                                 const float* __restrict__ a_dst, const int* __restrict__ rowstart,
                                                 const int* __restrict__ csr_src, const float* __restrict__ bias,
                                                 _Float16* __restrict__ oh, _Float16* __restrict__ ol,
                                                 const float* __restrict__ wvd, float* __restrict__ ad_out,
                                                 int N) {
  int w = (blockIdx.x * blockDim.x + threadIdx.x) >> 6;
  int lane = threadIdx.x & 63;
  if (w >= N) return;
  int s0 = rowstart[w];
  int s1 = rowstart[w + 1];
  int deg = s1 - s0;
  float ad = a_dst[w];

  int sA = 0;
  float eA = -3.0e38f;
  if (lane < deg) {
    sA = csr_src[s0 + lane];
    eA = lrelu(a_src[sA] + ad);
  }
  float m = eA;
  for (int j = s0 + 64 + lane; j < s1; j += 64) {
    int s = csr_src[j];
    m = fmaxf(m, lrelu(a_src[s] + ad));
  }
#pragma unroll
  for (int off = 32; off; off >>= 1) m = fmaxf(m, __shfl_xor(m, off, 64));

  float preg = (lane < deg) ? __expf(eA - m) : 0.f;
  float den = preg;
  for (int j = s0 + 64 + lane; j < s1; j += 64) {
    int s = csr_src[j];
    den += __expf(lrelu(a_src[s] + ad) - m);
  }
#pragma unroll
  for (int off = 32; off; off >>= 1) den += __shfl_xor(den, off, 64);
  float inv = 1.f / den;

  // quarter-wave uint4 gather; bound padded to multiple of 4 => every __shfl at FULL exec
  // (divergent-exec shfl corrupted rounds 2/9). Padded edges carry preg=0.
  const int q  = lane >> 4;
  const int sl = lane & 15;
  const uint4* hrow4 = (const uint4*)hbf;
  float acc[8];
#pragma unroll
  for (int i = 0; i < 8; ++i) acc[i] = 0.f;

  int lim  = deg < 64 ? deg : 64;
  int lim4 = (lim + 3) & ~3;
  for (int jj = 0; jj < lim4; jj += 4) {
    int e = jj + q;
    int s = __shfl(sA, e, 64);
    float wgt = __shfl(preg, e, 64) * inv;
    uint4 u = hrow4[(size_t)s * 16 + sl];
    acc[0] = fmaf(wgt, bflo(u.x), acc[0]);
    acc[1] = fmaf(wgt, bfhi(u.x), acc[1]);
    acc[2] = fmaf(wgt, bflo(u.y), acc[2]);
    acc[3] = fmaf(wgt, bfhi(u.y), acc[3]);
    acc[4] = fmaf(wgt, bflo(u.z), acc[4]);
    acc[5] = fmaf(wgt, bfhi(u.z), acc[5]);
    acc[6] = fmaf(wgt, bflo(u.w), acc[6]);
    acc[7] = fmaf(wgt, bfhi(u.w), acc[7]);
  }
  for (int j = s0 + 64 + q; j < s1; j += 4) {  // rare deg>64 tail: shfl-free
    int s = csr_src[j];
    float wgt = __expf(lrelu(a_src[s] + ad) - m) * inv;
    uint4 u = hrow4[(size_t)s * 16 + sl];
    acc[0] = fmaf(wgt, bflo(u.x), acc[0]);
    acc[1] = fmaf(wgt, bfhi(u.x), acc[1]);
    acc[2] = fmaf(wgt, bflo(u.y), acc[2]);
    acc[3] = fmaf(wgt, bfhi(u.y), acc[3]);
    acc[4] = fmaf(wgt, bflo(u.z), acc[4]);
    acc[5] = fmaf(wgt, bfhi(u.z), acc[5]);
    acc[6] = fmaf(wgt, bflo(u.w), acc[6]);
    acc[7] = fmaf(wgt, bfhi(u.w), acc[7]);
  }
#pragma unroll
  for (int i = 0; i < 8; ++i) {
    acc[i] += __shfl_xor(acc[i], 16, 64);
    acc[i] += __shfl_xor(acc[i], 32, 64);
  }
  if (q == 0) {
    float4 b0 = *(const float4*)&bias[8 * sl];
    float4 b1 = *(const float4*)&bias[8 * sl + 4];
    float v[8];
    v[0] = fmaxf(acc[0] + b0.x, 0.f);
    v[1] = fmaxf(acc[1] + b0.y, 0.f);
    v[2] = fmaxf(acc[2] + b0.z, 0.f);
    v[3] = fmaxf(acc[3] + b0.w, 0.f);
    v[4] = fmaxf(acc[4] + b1.x, 0.f);
    v[5] = fmaxf(acc[5] + b1.y, 0.f);
    v[6] = fmaxf(acc[6] + b1.z, 0.f);
    v[7] = fmaxf(acc[7] + b1.w, 0.f);
    half8 vh, vl;
#pragma unroll
    for (int i = 0; i < 8; ++i) {
      h2 s = split2h(v[i]);
      vh[i] = s.h;
      vl[i] = s.l;
    }
    size_t base = (size_t)w * 128 + 8 * sl;
    *(half8*)&oh[base] = vh;
    *(half8*)&ol[base] = vl;
    if (wvd) {
      float4 w0 = *(const float4*)&wvd[8 * sl];
      float4 w1 = *(const float4*)&wvd[8 * sl + 4];
      float dd = v[0] * w0.x + v[1] * w0.y + v[2] * w0.z + v[3] * w0.w
               + v[4] * w1.x + v[5] * w1.y + v[6] * w1.z + v[7] * w1.w;
      dd += __shfl_xor(dd, 1, 64);
      dd += __shfl_xor(dd, 2, 64);
      dd += __shfl_xor(dd, 4, 64);
      dd += __shfl_xor(dd, 8, 64);
      if (sl == 0) ad_out[w] = dd;
    }
  }
}

// ---------------- BatchNorm stats ----------------
__global__ __launch_bounds__(256) void bn_stats_k(const float* __restrict__ z, int N,
                                                  float* __restrict__ sums, float* __restrict__ sumsq) {
  __shared__ float ls[256], lq[256];
  int col = threadIdx.x & 63;
  int rg = threadIdx.x >> 6;
  float s = 0.f, q = 0.f;
  for (int r = blockIdx.x * 4 + rg; r < N; r += gridDim.x * 4) {
    float v = z[(size_t)r * 64 + col];
    s += v;
    q = fmaf(v, v, q);
  }
  ls[threadIdx.x] = s;
  lq[threadIdx.x] = q;
  __syncthreads();
  if (threadIdx.x < 64) {
    s = ls[col] + ls[col + 64] + ls[col + 128] + ls[col + 192];
    q = lq[col] + lq[col + 64] + lq[col + 128] + lq[col + 192];
    atomicAdd(&sums[col], s);
    atomicAdd(&sumsq[col], q);
  }
}

// ---------------- fused BN-finalize + BN-apply + ReLU + FC2 + log_softmax ----------------
__global__ __launch_bounds__(256) void fc2_lsm_k(const float* __restrict__ z,
                                                 const float* __restrict__ sums, const float* __restrict__ sumsq,
                                                 const float* __restrict__ gamma, const float* __restrict__ beta,
                                                 const float* __restrict__ w,
                                                 const float* __restrict__ b, float* __restrict__ out,
                                                 int N, float invN) {
  __shared__ float ssc[64], ssh[64];
  if (threadIdx.x < 64) {
    int c = threadIdx.x;
    float mean = sums[c] * invN;
    float var = sumsq[c] * invN - mean * mean;
    float rs = rsqrtf(var + BN_EPS);
    float sc = gamma[c] * rs;
    ssc[c] = sc;
    ssh[c] = beta[c] - mean * sc;
  }
  __syncthreads();
  int n = blockIdx.x * 256 + threadIdx.x;
  if (n >= N) return;
  float o[40];
#pragma unroll
  for (int c = 0; c < 40; ++c) o[c] = b[c];
  const float* zr = z + (size_t)n * 64;
  for (int k = 0; k < 64; ++k) {
    float v = fmaxf(fmaf(zr[k], ssc[k], ssh[k]), 0.f);
#pragma unroll
    for (int c = 0; c < 40; ++c) o[c] = fmaf(v, w[k * 40 + c], o[c]);
  }
  float mx = o[0];
#pragma unroll
  for (int c = 1; c < 40; ++c) mx = fmaxf(mx, o[c]);
  float s = 0.f;
#pragma unroll
  for (int c = 0; c < 40; ++c) s += __expf(o[c] - mx);
  float ls = __logf(s);
  float* orow = out + (size_t)n * 40;
#pragma unroll
  for (int c = 0; c < 40; ++c) orow[c] = o[c] - mx - ls;
}

// ---------------- launch ----------------
static inline char* al16(char* p) { return (char*)(((size_t)p + 15) & ~(size_t)15); }

extern "C" void kernel_launch(void* const* d_in, const int* in_sizes, int n_in,
                              void* d_out, int out_size, void* d_ws, size_t ws_size,
                              hipStream_t stream) {
  const float* x     = (const float*)d_in[0];
  const int*   eidx  = (const int*)d_in[1];
  const float* W1s   = (const float*)d_in[2];
  const float* W1d   = (const float*)d_in[3];
  const float* att1s = (const float*)d_in[4];
  const float* att1d = (const float*)d_in[5];
  const float* b1    = (const float*)d_in[6];
  const float* W2s   = (const float*)d_in[7];
  const float* W2d   = (const float*)d_in[8];
  const float* att2s = (const float*)d_in[9];
  const float* att2d = (const float*)d_in[10];
  const float* b2    = (const float*)d_in[11];
  const float* fc1w  = (const float*)d_in[12];
  const float* fc1b  = (const float*)d_in[13];
  const float* gamma = (const float*)d_in[14];
  const float* beta  = (const float*)d_in[15];
  const float* fc2w  = (const float*)d_in[16];
  const float* fc2b  = (const float*)d_in[17];
  float* out = (float*)d_out;

  const int N  = in_sizes[0] / 256;
  const int E  = in_sizes[1] / 2;
  const int ET = E + N;
  const int DIN = 256, H1 = 128;

  // workspace layout — deg/sums/sumsq contiguous at front for a single memset
  char* p = (char*)d_ws;
  int* deg      = (int*)p;     p += (size_t)N * 4;
  float* sums   = (float*)p;   p += 64 * 4;
  float* sumsq  = (float*)p;   p += 64 * 4;
  unsigned short* bhA = (unsigned short*)p; p += (size_t)N * 128 * 2;
  _Float16* hAh = (_Float16*)p;  p += (size_t)N * 128 * 2;
  _Float16* hAl = (_Float16*)p;  p += (size_t)N * 128 * 2;
  float* hF = (float*)p;         p += (size_t)N * 64 * 4;
  int* rowstart = (int*)p;     p += (size_t)(N + 1) * 4;
  int* cursor   = (int*)p;     p += (size_t)N * 4;
  int* csr_src  = (int*)p;     p += (size_t)ET * 4;
  float* a_src  = (float*)p;   p += (size_t)N * 4;
  float* a_dst  = (float*)p;   p += (size_t)N * 4;
  float* a_dst2 = (float*)p;   p += (size_t)N * 4;
  float* wvd1   = (float*)p;   p += 256 * 4;
  float* wvd2   = (float*)p;   p += 128 * 4;
  int* bsum     = (int*)p;     p += 256 * 4;
  p = al16(p);
  _Float16* B1h = (_Float16*)p; p += (size_t)256 * 128 * 2;
  _Float16* B1l = (_Float16*)p; p += (size_t)256 * 128 * 2;
  _Float16* B2h = (_Float16*)p; p += (size_t)128 * 128 * 2;
  _Float16* B2l = (_Float16*)p; p += (size_t)128 * 128 * 2;
  _Float16* Bfh = (_Float16*)p; p += (size_t)128 * 64 * 2;
  _Float16* Bfl = (_Float16*)p; p += (size_t)128 * 64 * 2;

  const int* esrc = eidx;
  const int* edst = eidx + E;

  // one memset zeroes deg + sums + sumsq
  hipMemsetAsync(deg, 0, (size_t)N * 4 + 512, stream);

  deg_count_k<<<(ET + 255) / 256, 256, 0, stream>>>(edst, E, N, deg);
  int nb = (N + 1023) / 1024;
  scan1_k<<<nb, 1024, 0, stream>>>(deg, N, rowstart, bsum);
  scan3_k<<<(N + 255) / 256, 256, 0, stream>>>(rowstart, bsum, N, nb, ET, cursor);
  {
    const int NR = 8;
    int step = (N + NR - 1) / NR;
    for (int r = 0; r < NR; ++r) {
      int d0 = r * step;
      int d1 = d0 + step < N ? d0 + step : N;
      scatter_range_k<<<(ET + 255) / 256, 256, 0, stream>>>(esrc, edst, E, N, d0, d1, cursor, csr_src);
    }
  }

  // fused weight prep: 3 B-splits + 2 fold-matvecs in one dispatch
  prep_k<<<124, 256, 0, stream>>>(W1s, W2s, fc1w, W1d, att1d, W2d, att2d,
                                  B1h, B1l, B2h, B2l, Bfh, Bfl, wvd1, wvd2);

  const int gemm_blocks = (N + 127) / 128;

  // ---- GAT layer 1: gemm emits bf16 h + fused a_src (C.att1s) + fused a_dst (x.wvd1) ----
  gemm3h_k<128><<<gemm_blocks, 256, 0, stream>>>(x, B1h, B1l, (float*)nullptr, bhA, att1s, a_src,
                                                 wvd1, a_dst, N, DIN, (const float*)nullptr);
  gat_agg_k<<<(N + 3) / 4, 256, 0, stream>>>(bhA, a_src, a_dst, rowstart, csr_src, b1,
                                             hAh, hAl, wvd2, a_dst2, N);

  // ---- GAT layer 2 (A pre-split f16; a_dst2 fused in L1 agg) ----
  gemm3p_k<128><<<gemm_blocks, 256, 0, stream>>>(hAh, hAl, B2h, B2l, (float*)nullptr, bhA, att2s, a_src,
                                                 N, H1, (const float*)nullptr);
  gat_agg_k<<<(N + 3) / 4, 256, 0, stream>>>(bhA, a_src, a_dst2, rowstart, csr_src, b2,
                                             hAh, hAl, (const float*)nullptr, (float*)nullptr, N);

  // ---- FC1 -> BN-stats -> fused BN+FC2+log_softmax ----
  gemm3p_k<64><<<gemm_blocks, 256, 0, stream>>>(hAh, hAl, Bfh, Bfl, hF, (unsigned short*)nullptr,
                                                (const float*)nullptr, (float*)nullptr, N, H1, fc1b);
  bn_stats_k<<<512, 256, 0, stream>>>(hF, N, sums, sumsq);
  fc2_lsm_k<<<(N + 255) / 256, 256, 0, stream>>>(hF, sums, sumsq, gamma, beta, fc2w, fc2b, out,
                                                 N, 1.0f / (float)N);
}